// Round 7
// baseline (2000.500 us; speedup 1.0000x reference)
//
#include <hip/hip_runtime.h>

#define CDIV(a,b) (((a)+(b)-1)/(b))
#define EE 40000
#define TOTROWS 170000
#define NDOFF 60001
#define NCHK 59

typedef unsigned short ushort_t;
typedef short bf16x8 __attribute__((ext_vector_type(8)));
typedef float f32x4 __attribute__((ext_vector_type(4)));

__device__ __forceinline__ float eluf(float x) { return x > 0.f ? x : expm1f(x); }
__device__ __forceinline__ float sigf(float x) { return 1.f / (1.f + expf(-x)); }
__device__ __forceinline__ float b2f(ushort_t u) { return __uint_as_float(((unsigned)u) << 16); }
__device__ __forceinline__ ushort_t f2b(float f) {
  unsigned x = __float_as_uint(f);
  x += 0x7FFFu + ((x >> 16) & 1u);
  return (ushort_t)(x >> 16);
}
__device__ __forceinline__ unsigned pk2(float lo, float hi) {
  return (unsigned)f2b(lo) | ((unsigned)f2b(hi) << 16);
}
__device__ __forceinline__ float2 b2f2(unsigned u) {
  return make_float2(__uint_as_float(u << 16), __uint_as_float(u & 0xFFFF0000u));
}

__constant__ const int NDD_C[7] = {20000, 20000, 40000, 40000, 40000, 40000, 60000};

// ======== shared MFMA helpers ========
template<int BN>
__device__ __forceinline__ void stage_B(char* Bs, int tid, const ushort_t* Bt, const ushort_t* Bt2) {
#pragma unroll
  for (int i = 0; i < BN / 16; i++) {
    int u = tid + i * 256;
    int nrow = u >> 4;
    const ushort_t* sp = (BN == 256 && u >= 2048) ? (Bt2 + (size_t)(u - 2048) * 8)
                                                  : (Bt + (size_t)u * 8);
    uint4 w = *(const uint4*)sp;
    *(uint4*)(Bs + ((u * 16) ^ ((nrow & 7) << 4))) = w;
  }
}

__device__ __forceinline__ void stage_A_bf16(char* As, int tid, const ushort_t* Ab, int base, int n) {
#pragma unroll
  for (int i = 0; i < 4; i++) {
    int u = tid + i * 256;
    int row = u >> 4;
    int grow = base + row;
    uint4 v = make_uint4(0, 0, 0, 0);
    if (grow < n) v = *(const uint4*)&Ab[(size_t)grow * 128 + (u & 15) * 8];
    *(uint4*)(As + ((u * 16) ^ ((row & 7) << 4))) = v;
  }
}

template<int NF>
__device__ __forceinline__ void mfma_core(const char* As, const char* Bs, int lane, int wcol,
                                          f32x4 (&acc)[4][NF]) {
  int i16 = lane & 15, seg = lane >> 4;
#pragma unroll
  for (int s = 0; s < 4; s++) {
    bf16x8 a[4], b[NF];
#pragma unroll
    for (int m = 0; m < 4; m++) {
      int row = m * 16 + i16;
      a[m] = *(const bf16x8*)(As + ((row * 256 + s * 64 + seg * 16) ^ ((row & 7) << 4)));
    }
#pragma unroll
    for (int nn = 0; nn < NF; nn++) {
      int nr = wcol + nn * 16 + i16;
      b[nn] = *(const bf16x8*)(Bs + ((nr * 256 + s * 64 + seg * 16) ^ ((nr & 7) << 4)));
    }
#pragma unroll
    for (int m = 0; m < 4; m++)
#pragma unroll
      for (int nn = 0; nn < NF; nn++)
        acc[m][nn] = __builtin_amdgcn_mfma_f32_16x16x32_bf16(a[m], b[nn], acc[m][nn], 0, 0, 0);
  }
}

// ---------------- scalar prep
__global__ void prep_scalars(const float* __restrict__ theta, const float* __restrict__ rel_imp,
                             float* __restrict__ scal) {
  int t = threadIdx.x;
  if (t < 7) scal[t] = 1.f - sigf(theta[t]);
  if (t < 21) {
    const int partner[7] = {1, 0, 4, 5, 2, 3, -1};
    int l = t / 7, r = t % 7;
    float rw = sigf(rel_imp[t]);
    float w;
    if (partner[r] < 0) w = 1.f;
    else {
      float rwp = sigf(rel_imp[l * 7 + partner[r]]);
      float e0 = expf(rw), e1 = expf(rwp);
      w = e0 / (e0 + e1);
    }
    scal[8 + t] = w * rw;
  }
}

// ---------------- weight transpose + bf16 cast
__global__ __launch_bounds__(256) void transpose_weights(
    const float* __restrict__ Wq, const float* __restrict__ Wk, const float* __restrict__ Wv,
    const float* __restrict__ Wmsg, const float* __restrict__ Wo, const float* __restrict__ We1,
    ushort_t* __restrict__ Wt) {
  int mat = blockIdx.x;
  const float* src;
  if (mat < 21)      src = Wq   + (size_t)mat * 16384;
  else if (mat < 42) src = Wk   + (size_t)(mat - 21) * 16384;
  else if (mat < 63) src = Wv   + (size_t)(mat - 42) * 16384;
  else if (mat < 84) src = Wmsg + (size_t)(mat - 63) * 16384;
  else if (mat < 99) src = Wo   + (size_t)(mat - 84) * 16384;
  else               src = We1  + (size_t)(mat - 99) * 16384;
  __shared__ ushort_t lds[16384];
  int t = threadIdx.x;
  for (int i = 0; i < 64; i++) {
    int u = t + i * 256;            // u = k*128 + n
    int k = u >> 7;
    int byte = (u * 2) ^ ((k & 15) << 2);
    *(ushort_t*)((char*)lds + byte) = f2b(src[u]);
  }
  __syncthreads();
  ushort_t* dst = Wt + (size_t)mat * 16384;
  for (int i = 0; i < 64; i++) {
    int u = t + i * 256;            // u = n*128 + k
    int n = u >> 7, k = u & 127;
    int byte = ((k * 128 + n) * 2) ^ ((k & 15) << 2);
    dst[u] = *(ushort_t*)((char*)lds + byte);
  }
}

__global__ void transpose_wr1(const float* __restrict__ Wr1, ushort_t* __restrict__ Wt101) {
  int u = blockIdx.x * 256 + threadIdx.x;   // 8192
  int n = u >> 7, k = u & 127;
  Wt101[u] = f2b(Wr1[k * 64 + n]);
}

// ---------------- input projection: LDS-staged, templated-F, 64 rows/block
template<int F>
__device__ __forceinline__ void inproj_compute(const float* xs, const float* Ws, const float* b2,
                                               ushort_t* hptr, int base, int n, int tid) {
  int cp = tid & 63, rg = tid >> 6;     // cols 2cp,2cp+1 ; rows rg*16..rg*16+15
  float wc0[F], wc1[F];
#pragma unroll
  for (int f = 0; f < F; f++) {
    wc0[f] = Ws[f * 128 + cp * 2];
    wc1[f] = Ws[f * 128 + cp * 2 + 1];
  }
  float bb0 = b2[cp * 2], bb1 = b2[cp * 2 + 1];
  for (int i = 0; i < 16; i++) {
    int row = rg * 16 + i, grow = base + row;
    if (grow >= n) break;
    float a0 = bb0, a1 = bb1;
#pragma unroll
    for (int f = 0; f < F; f++) {
      float xv = xs[row * F + f];
      a0 = fmaf(xv, wc0[f], a0);
      a1 = fmaf(xv, wc1[f], a1);
    }
    *(unsigned*)&hptr[(size_t)grow * 128 + cp * 2] = pk2(eluf(a0), eluf(a1));
  }
}

__global__ __launch_bounds__(256) void in_proj_all(
    const float* __restrict__ x0, const float* __restrict__ x1, const float* __restrict__ x2,
    const float* __restrict__ x3, const float* __restrict__ x4,
    const float* __restrict__ W0, const float* __restrict__ W1, const float* __restrict__ W2,
    const float* __restrict__ W3, const float* __restrict__ W4,
    const float* __restrict__ b_in, ushort_t* __restrict__ h) {
  __shared__ float xs[64 * 22];
  __shared__ float Ws[22 * 128];
  int bb = blockIdx.x, tid = threadIdx.x;
  int ti, lb;
  if (bb < 938)       { ti = 0; lb = bb; }
  else if (bb < 1251) { ti = 1; lb = bb - 938; }
  else if (bb < 1876) { ti = 2; lb = bb - 1251; }
  else if (bb < 2501) { ti = 3; lb = bb - 1876; }
  else                { ti = 4; lb = bb - 2501; }
  const int ROFF_[5] = {0, 60000, 80000, 120000, 160000};
  const int NCNT_[5] = {60000, 20000, 40000, 40000, 10000};
  const int FEAT_[5] = {22, 6, 14, 5, 9};
  const float* xp = (ti == 0) ? x0 : (ti == 1) ? x1 : (ti == 2) ? x2 : (ti == 3) ? x3 : x4;
  const float* Wp = (ti == 0) ? W0 : (ti == 1) ? W1 : (ti == 2) ? W2 : (ti == 3) ? W3 : W4;
  int F = FEAT_[ti], n = NCNT_[ti], base = lb * 64;
  for (int u = tid; u < F * 128; u += 256) Ws[u] = Wp[u];
  for (int u = tid; u < 64 * F; u += 256) {
    int row = u / F, f = u - row * F, grow = base + row;
    xs[u] = (grow < n) ? xp[(size_t)grow * F + f] : 0.f;
  }
  __syncthreads();
  ushort_t* hptr = h + (size_t)ROFF_[ti] * 128;
  const float* b2 = b_in + ti * 128;
  switch (ti) {
    case 0: inproj_compute<22>(xs, Ws, b2, hptr, base, n, tid); break;
    case 1: inproj_compute<6>(xs, Ws, b2, hptr, base, n, tid); break;
    case 2: inproj_compute<14>(xs, Ws, b2, hptr, base, n, tid); break;
    case 3: inproj_compute<5>(xs, Ws, b2, hptr, base, n, tid); break;
    default: inproj_compute<9>(xs, Ws, b2, hptr, base, n, tid); break;
  }
}

// ================= CSR build (per relation, by dst) =================
__global__ void csr_clear(int* __restrict__ counts) {
  int idx = blockIdx.x * 256 + threadIdx.x;
  if (idx < 7 * NDOFF) counts[idx] = 0;
}

__global__ void csr_hist(const int* __restrict__ ei, int* __restrict__ counts) {
  int idx = blockIdx.x * 256 + threadIdx.x;
  if (idx >= 7 * EE) return;
  int r = idx / EE, e = idx - r * EE;
  int d = ei[(size_t)r * 2 * EE + EE + e];
  atomicAdd(&counts[r * NDOFF + d], 1);
}

__global__ __launch_bounds__(256) void csr_chunk(const int* __restrict__ counts, int* __restrict__ chunkSums) {
  int bb = blockIdx.x;                 // 7*NCHK
  int r = bb / NCHK, c = bb - r * NCHK;
  int ndd = NDD_C[r];
  int t = threadIdx.x;
  int v = 0;
#pragma unroll
  for (int j = 0; j < 4; j++) {
    int idx = c * 1024 + t + j * 256;
    if (idx < ndd) v += counts[r * NDOFF + idx];
  }
#pragma unroll
  for (int mm = 32; mm; mm >>= 1) v += __shfl_xor(v, mm);
  __shared__ int ws_[4];
  if ((t & 63) == 0) ws_[t >> 6] = v;
  __syncthreads();
  if (t == 0) chunkSums[bb] = ws_[0] + ws_[1] + ws_[2] + ws_[3];
}

__global__ void csr_chunkscan(const int* __restrict__ chunkSums, int* __restrict__ chunkOffs) {
  int r = threadIdx.x;
  if (r >= 7) return;
  int run = 0;
  for (int c = 0; c < NCHK; c++) {
    chunkOffs[r * NCHK + c] = run;
    run += chunkSums[r * NCHK + c];
  }
}

__global__ __launch_bounds__(1024) void csr_scan_final(
    const int* __restrict__ counts, const int* __restrict__ chunkOffs,
    int* __restrict__ offs, int* __restrict__ cursor) {
  int bb = blockIdx.x;
  int r = bb / NCHK, c = bb - r * NCHK;
  int ndd = NDD_C[r];
  int t = threadIdx.x;
  int idx = c * 1024 + t;
  int v = (idx < ndd) ? counts[r * NDOFF + idx] : 0;
  __shared__ int sc[1024];
  sc[t] = v;
  __syncthreads();
  for (int s = 1; s < 1024; s <<= 1) {
    int add = (t >= s) ? sc[t - s] : 0;
    __syncthreads();
    sc[t] += add;
    __syncthreads();
  }
  if (idx < ndd) {
    int excl = chunkOffs[r * NCHK + c] + sc[t] - v;
    offs[r * NDOFF + idx] = excl;
    cursor[r * NDOFF + idx] = excl;
  }
  if (t == 0 && c == 0) offs[r * NDOFF + ndd] = EE;
}

// scatter src + ew into CSR order (removes indirection in the hot loop)
__global__ void csr_scatter(const int* __restrict__ ei, const float* __restrict__ ew,
                            int* __restrict__ cursor, int* __restrict__ src_csr,
                            float* __restrict__ ew_csr) {
  int idx = blockIdx.x * 256 + threadIdx.x;
  if (idx >= 7 * EE) return;
  int r = idx / EE, e = idx - r * EE;
  int d = ei[(size_t)r * 2 * EE + EE + e];
  int s = ei[(size_t)r * 2 * EE + e];
  int slot = atomicAdd(&cursor[r * NDOFF + d], 1);
  src_csr[r * EE + slot] = s;
  ew_csr[r * EE + slot] = ew[(size_t)r * EE + e];
}

// ---------------- fused QKV projections
__global__ __launch_bounds__(256) void qkv_proj(
    const ushort_t* __restrict__ hd, const ushort_t* __restrict__ hs,
    const ushort_t* __restrict__ WtQ, const ushort_t* __restrict__ WtK, const ushort_t* __restrict__ WtV,
    ushort_t* __restrict__ Qb, ushort_t* __restrict__ Kb, ushort_t* __restrict__ Vb,
    int ndd, int nds) {
  __shared__ char sm[16384 + 65536];
  char* As = sm;
  char* Bs = sm + 16384;
  int tid = threadIdx.x;
  int nqb = (ndd + 63) >> 6;
  int lane = tid & 63, wv = tid >> 6;
  int i16 = lane & 15, seg = lane >> 4;

  if ((int)blockIdx.x < nqb) {
    int base = blockIdx.x * 64;
    stage_B<128>(Bs, tid, WtQ, nullptr);
    stage_A_bf16(As, tid, hd, base, ndd);
    __syncthreads();
    f32x4 acc[4][2] = {};
    mfma_core<2>(As, Bs, lane, wv * 32, acc);
#pragma unroll
    for (int m = 0; m < 4; m++)
#pragma unroll
      for (int i = 0; i < 4; i++) {
        int grow = base + m * 16 + seg * 4 + i;
        if (grow >= ndd) continue;
#pragma unroll
        for (int nn = 0; nn < 2; nn++) {
          int col = wv * 32 + nn * 16 + i16;
          Qb[(size_t)grow * 128 + col] = f2b(acc[m][nn][i]);
        }
      }
  } else {
    int base = (blockIdx.x - nqb) * 64;
    stage_B<256>(Bs, tid, WtK, WtV);
    stage_A_bf16(As, tid, hs, base, nds);
    __syncthreads();
    f32x4 acc[4][4] = {};
    mfma_core<4>(As, Bs, lane, wv * 64, acc);
#pragma unroll
    for (int m = 0; m < 4; m++)
#pragma unroll
      for (int i = 0; i < 4; i++) {
        int grow = base + m * 16 + seg * 4 + i;
        if (grow >= nds) continue;
#pragma unroll
        for (int nn = 0; nn < 4; nn++) {
          int col = wv * 64 + nn * 16 + i16;
          ushort_t val = f2b(acc[m][nn][i]);
          if (col < 128) Kb[(size_t)grow * 128 + col] = val;
          else           Vb[(size_t)grow * 128 + col - 128] = val;
        }
      }
  }
}

// ---------------- fused CSR attention + Wmsg GEMM + comb accumulate
// block = 64 dst rows; 4 waves x 16 nodes online-softmax -> swizzled LDS A tile -> MFMA
// MODE 4: comb = coef*(acc + deg*bmsg); MODE 1: comb += ...
template<int MODE>
__global__ __launch_bounds__(256) void attn_msg(
    const ushort_t* __restrict__ Qb, const ushort_t* __restrict__ Kb, const ushort_t* __restrict__ Vb,
    const int* __restrict__ offs, const int* __restrict__ src_csr, const float* __restrict__ ew_csr,
    const float* __restrict__ ews, const ushort_t* __restrict__ WtM,
    ushort_t* __restrict__ comb, int ndd,
    const float* __restrict__ coefp, const float* __restrict__ bvec) {
  __shared__ char sm[16384 + 32768];
  __shared__ float degs[64];
  char* As = sm;
  char* Bs = sm + 16384;
  int tid = threadIdx.x;
  int base = blockIdx.x * 64;
  int lane = tid & 63, wv = tid >> 6;

  stage_B<128>(Bs, tid, WtM, nullptr);
  float escale = ews[0] * 0.17677669529663687f;

  for (int i = 0; i < 16; i++) {
    int rl = wv * 16 + i;
    int node = base + rl;
    float o0 = 0.f, o1 = 0.f, dg = 0.f;
    if (node < ndd) {
      int beg = offs[node], end = offs[node + 1];
      dg = (float)(end - beg);
      float q0 = b2f(Qb[(size_t)node * 128 + lane]);
      float q1 = b2f(Qb[(size_t)node * 128 + 64 + lane]);
      float m0 = -3.0e38f, m1 = -3.0e38f, z0 = 0.f, z1 = 0.f, a0 = 0.f, a1 = 0.f;
      for (int p = beg; p < end; p++) {
        int s = src_csr[p];
        float wgt = ew_csr[p] * escale;
        float k0 = b2f(Kb[(size_t)s * 128 + lane]);
        float k1 = b2f(Kb[(size_t)s * 128 + 64 + lane]);
        float p0 = q0 * k0, p1 = q1 * k1;
#pragma unroll
        for (int mm = 16; mm; mm >>= 1) {
          p0 += __shfl_xor(p0, mm);
          p1 += __shfl_xor(p1, mm);
        }
        float s0 = p0 * wgt, s1 = p1 * wgt;
        float nm0 = fmaxf(m0, s0), nm1 = fmaxf(m1, s1);
        float r0 = expf(m0 - nm0), r1 = expf(m1 - nm1);
        float e0 = expf(s0 - nm0), e1 = expf(s1 - nm1);
        float v0 = b2f(Vb[(size_t)s * 128 + lane]);
        float v1 = b2f(Vb[(size_t)s * 128 + 64 + lane]);
        z0 = z0 * r0 + e0; a0 = a0 * r0 + e0 * v0; m0 = nm0;
        z1 = z1 * r1 + e1; a1 = a1 * r1 + e1 * v1; m1 = nm1;
      }
      o0 = a0 / (z0 + 1e-10f);
      o1 = a1 / (z1 + 1e-10f);
    }
    *(ushort_t*)(As + ((rl * 256 + lane * 2) ^ ((rl & 7) << 4))) = f2b(o0);
    *(ushort_t*)(As + ((rl * 256 + 128 + lane * 2) ^ ((rl & 7) << 4))) = f2b(o1);
    if (lane == 0) degs[rl] = dg;
  }
  __syncthreads();

  int i16 = lane & 15, seg = lane >> 4;
  f32x4 acc[4][2] = {};
  mfma_core<2>(As, Bs, lane, wv * 32, acc);
  float coef = *coefp;
#pragma unroll
  for (int m = 0; m < 4; m++)
#pragma unroll
    for (int i = 0; i < 4; i++) {
      int rl = m * 16 + seg * 4 + i;
      int grow = base + rl;
      if (grow >= ndd) continue;
      float dg = degs[rl];
#pragma unroll
      for (int nn = 0; nn < 2; nn++) {
        int col = wv * 32 + nn * 16 + i16;
        ushort_t* cp = &comb[(size_t)grow * 128 + col];
        float mv = coef * (acc[m][nn][i] + dg * bvec[col]);
        if (MODE == 1) mv += b2f(*cp);
        *cp = f2b(mv);
      }
    }
}

// ---------------- Pcat GEMM (BN=256, split weights)
__global__ __launch_bounds__(256) void gemm_pcat(
    const ushort_t* __restrict__ Ap, const ushort_t* __restrict__ Bt, const ushort_t* __restrict__ Bt2,
    ushort_t* __restrict__ C1, int n) {
  __shared__ char sm[16384 + 65536];
  char* As = sm;
  char* Bs = sm + 16384;
  int tid = threadIdx.x;
  int base = blockIdx.x * 64;
  stage_B<256>(Bs, tid, Bt, Bt2);
  stage_A_bf16(As, tid, Ap, base, n);
  __syncthreads();
  int lane = tid & 63, wv = tid >> 6;
  int i16 = lane & 15, seg = lane >> 4;
  f32x4 acc[4][4] = {};
  mfma_core<4>(As, Bs, lane, wv * 64, acc);
#pragma unroll
  for (int m = 0; m < 4; m++)
#pragma unroll
    for (int i = 0; i < 4; i++) {
      int grow = base + m * 16 + seg * 4 + i;
      if (grow >= n) continue;
#pragma unroll
      for (int nn = 0; nn < 4; nn++) {
        int col = wv * 64 + nn * 16 + i16;
        C1[(size_t)grow * 256 + col] = f2b(acc[m][nn][i]);
      }
    }
}

// ---------------- batched Wo GEMM + residual + LN + elu, + AIAgent elu tail
#define WO_C1 938
#define WO_C2 1251
#define WO_C3 1876
#define WO_C4 2501
#define WO_TOTAL 2814
__global__ __launch_bounds__(256) void wo_ln_all(
    ushort_t* __restrict__ h, const ushort_t* __restrict__ comb, const ushort_t* __restrict__ Wt,
    const float* __restrict__ bo, const float* __restrict__ lng, const float* __restrict__ lnb, int l) {
  int bb = blockIdx.x;
  int tid = threadIdx.x;
  if (bb >= WO_C4) {
    int idx16 = (bb - WO_C4) * 256 + tid;
    if (idx16 >= 80000) return;
    ushort_t* p = h + (size_t)160000 * 128 + (size_t)idx16 * 16;
    uint4 v0 = *(uint4*)p, v1 = *(uint4*)(p + 8);
    unsigned* u0 = (unsigned*)&v0;
    unsigned* u1 = (unsigned*)&v1;
#pragma unroll
    for (int i = 0; i < 4; i++) {
      float2 a = b2f2(u0[i]); u0[i] = pk2(eluf(a.x), eluf(a.y));
      float2 b = b2f2(u1[i]); u1[i] = pk2(eluf(b.x), eluf(b.y));
    }
    *(uint4*)p = v0; *(uint4*)(p + 8) = v1;
    return;
  }
  int ti, lb;
  if (bb < WO_C1)      { ti = 0; lb = bb; }
  else if (bb < WO_C2) { ti = 1; lb = bb - WO_C1; }
  else if (bb < WO_C3) { ti = 2; lb = bb - WO_C2; }
  else                 { ti = 3; lb = bb - WO_C3; }
  const int ROFF_[4] = {0, 60000, 80000, 120000};
  const int NCNT4_[4] = {60000, 20000, 40000, 40000};
  int n = NCNT4_[ti];
  int base = lb * 64;
  int li = l * 5 + ti;
  const ushort_t* A = comb + (size_t)ROFF_[ti] * 128;
  ushort_t* C1 = h + (size_t)ROFF_[ti] * 128;
  const ushort_t* Bt = Wt + (size_t)(84 + li) * 16384;
  const float* bvec = bo + (size_t)li * 128;
  const float* g = lng + (size_t)li * 128;
  const float* b = lnb + (size_t)li * 128;

  __shared__ char sm[16384 + 32768];
  char* As = sm;
  char* Bs = sm + 16384;
  stage_B<128>(Bs, tid, Bt, nullptr);
  stage_A_bf16(As, tid, A, base, n);
  __syncthreads();
  int lane = tid & 63, wv = tid >> 6;
  int i16 = lane & 15, seg = lane >> 4;
  f32x4 acc[4][2] = {};
  mfma_core<2>(As, Bs, lane, wv * 32, acc);

  __syncthreads();
  float* Ys = (float*)Bs;
#pragma unroll
  for (int m = 0; m < 4; m++)
#pragma unroll
    for (int i = 0; i < 4; i++) {
      int rl = m * 16 + seg * 4 + i;
      int grow = base + rl;
      if (grow >= n) continue;
#pragma unroll
      for (int nn = 0; nn < 2; nn++) {
        int col = wv * 32 + nn * 16 + i16;
        Ys[rl * 128 + col] = acc[m][nn][i] + b2f(C1[(size_t)grow * 128 + col]) + bvec[col];
      }
    }
  __syncthreads();
  for (int rr = 0; rr < 16; rr++) {
    int rl = wv * 16 + rr;
    int grow = base + rl;
    if (grow >= n) continue;
    float y0 = Ys[rl * 128 + lane], y1 = Ys[rl * 128 + 64 + lane];
    float sum = y0 + y1;
#pragma unroll
    for (int mm = 32; mm; mm >>= 1) sum += __shfl_xor(sum, mm);
    float mu = sum * (1.f / 128.f);
    float d0 = y0 - mu, d1 = y1 - mu;
    float vs = d0 * d0 + d1 * d1;
#pragma unroll
    for (int mm = 32; mm; mm >>= 1) vs += __shfl_xor(vs, mm);
    float rs = rsqrtf(vs * (1.f / 128.f) + 1e-5f);
    C1[(size_t)grow * 128 + lane]      = f2b(eluf(d0 * rs * g[lane] + b[lane]));
    C1[(size_t)grow * 128 + 64 + lane] = f2b(eluf(d1 * rs * g[64 + lane] + b[64 + lane]));
  }
}

// ---------------- MFMA risk head
__global__ __launch_bounds__(256) void risk_mfma(
    const ushort_t* __restrict__ Hh, const ushort_t* __restrict__ Wt101,
    const float* __restrict__ br1, const float* __restrict__ Wr2, const float* __restrict__ br2,
    float* __restrict__ out) {
  __shared__ char sm[16384 + 16384 + 64 * 68 * 4];
  char* As = sm;
  char* Bs = sm + 16384;
  float* Hs = (float*)(sm + 32768);
  int tid = threadIdx.x;
  int base = blockIdx.x * 64;
#pragma unroll
  for (int i = 0; i < 4; i++) {
    int u = tid + i * 256;
    int nrow = u >> 4;
    uint4 w = *(const uint4*)(Wt101 + (size_t)u * 8);
    *(uint4*)(Bs + ((u * 16) ^ ((nrow & 7) << 4))) = w;
  }
  stage_A_bf16(As, tid, Hh, base, TOTROWS);
  __syncthreads();
  int lane = tid & 63, wv = tid >> 6;
  int i16 = lane & 15, seg = lane >> 4;
  f32x4 acc[4][1] = {};
  mfma_core<1>(As, Bs, lane, wv * 16, acc);
#pragma unroll
  for (int m = 0; m < 4; m++)
#pragma unroll
    for (int i = 0; i < 4; i++) {
      int rl = m * 16 + seg * 4 + i;
      int col = wv * 16 + i16;
      Hs[rl * 68 + col] = eluf(acc[m][0][i] + br1[col]);
    }
  __syncthreads();
  float wr2r = Wr2[lane];
  for (int rr = 0; rr < 16; rr++) {
    int rl = wv * 16 + rr;
    int grow = base + rl;
    float v = Hs[rl * 68 + lane] * wr2r;
#pragma unroll
    for (int mm = 32; mm; mm >>= 1) v += __shfl_xor(v, mm);
    if (lane == 0 && grow < TOTROWS) out[grow] = sigf(v + br2[0]);
  }
}

// ---------------- batched edge heads
__global__ __launch_bounds__(256) void edge_combine_all(
    const ushort_t* __restrict__ Pcat, const int* __restrict__ ei,
    const float* __restrict__ be1, const float* __restrict__ We2,
    const float* __restrict__ be2, float* __restrict__ out) {
  const int RSI_[7] = {0, 1, 0, 0, 2, 4, 0};
  const int RDI_[7] = {1, 1, 2, 3, 2, 3, 0};
  const int ROFF_[5] = {0, 60000, 80000, 120000, 160000};
  int bb = blockIdx.x;
  int r = bb / 10000;
  int lane = threadIdx.x & 63;
  int e = (bb % 10000) * 4 + (threadIdx.x >> 6);
  const int* src = ei + (size_t)r * 2 * EE;
  const int* dst = src + EE;
  int s = src[e], d = dst[e];
  const ushort_t* p1 = Pcat + ((size_t)(ROFF_[RSI_[r]] + s)) * 256;
  const ushort_t* p2 = Pcat + ((size_t)(ROFF_[RDI_[r]] + d)) * 256 + 128;
  float h0 = eluf(b2f(p1[lane])      + b2f(p2[lane])      + be1[lane]);
  float h1 = eluf(b2f(p1[64 + lane]) + b2f(p2[64 + lane]) + be1[64 + lane]);
  float v = h0 * We2[lane] + h1 * We2[64 + lane];
#pragma unroll
  for (int mm = 32; mm; mm >>= 1) v += __shfl_xor(v, mm);
  if (lane == 0) out[TOTROWS + (size_t)r * EE + e] = sigf(v + be2[0]);
}

extern "C" void kernel_launch(void* const* d_in, const int* in_sizes, int n_in,
                              void* d_out, int out_size, void* d_ws, size_t ws_size,
                              hipStream_t stream) {
  (void)in_sizes; (void)n_in; (void)out_size;
  static const int NCNT_[5] = {60000, 20000, 40000, 40000, 10000};
  static const int RSI[7] = {0, 1, 0, 0, 2, 4, 0};
  static const int RDI[7] = {1, 1, 2, 3, 2, 3, 0};
  static const int RFIRST[7] = {1, 0, 1, 1, 0, 0, 1};
  static const int ROFF[5] = {0, 60000, 80000, 120000, 160000};

  const float* x[5];    for (int i = 0; i < 5; i++) x[i] = (const float*)d_in[i];
  const int*   ei     = (const int*)d_in[5];
  const float* ew     = (const float*)d_in[6];
  const float* theta  = (const float*)d_in[7];
  const float* Win[5]; for (int i = 0; i < 5; i++) Win[i] = (const float*)d_in[8 + i];
  const float* b_in   = (const float*)d_in[13];
  const float* Wq     = (const float*)d_in[14];
  const float* Wk     = (const float*)d_in[15];
  const float* Wv     = (const float*)d_in[16];
  const float* Wmsg   = (const float*)d_in[17];
  const float* bmsg   = (const float*)d_in[18];
  const float* relimp = (const float*)d_in[19];
  const float* Wo     = (const float*)d_in[20];
  const float* bo     = (const float*)d_in[21];
  const float* lng    = (const float*)d_in[22];
  const float* lnb    = (const float*)d_in[23];
  const float* Wr1    = (const float*)d_in[24];
  const float* br1    = (const float*)d_in[25];
  const float* Wr2    = (const float*)d_in[26];
  const float* br2    = (const float*)d_in[27];
  const float* We1    = (const float*)d_in[28];
  const float* be1    = (const float*)d_in[29];
  const float* We2    = (const float*)d_in[30];
  const float* be2    = (const float*)d_in[31];
  float* out = (float*)d_out;

  // ---- workspace (~147 MB) ----
  char* ws = (char*)d_ws;
  size_t off = 0;
  auto alloc = [&](size_t bytes) -> void* {
    void* p = (void*)(ws + off);
    off = (off + bytes + 255) & ~(size_t)255;
    return p;
  };
  ushort_t* h    = (ushort_t*)alloc((size_t)TOTROWS * 128 * 2);
  ushort_t* comb = (ushort_t*)alloc((size_t)TOTROWS * 128 * 2);
  ushort_t* Qb   = (ushort_t*)alloc((size_t)60000 * 128 * 2);
  ushort_t* Kb   = (ushort_t*)alloc((size_t)60000 * 128 * 2);
  ushort_t* Vb   = (ushort_t*)alloc((size_t)60000 * 128 * 2);
  ushort_t* Wt = (ushort_t*)alloc((size_t)102 * 16384 * 2);
  int* counts  = (int*)alloc((size_t)7 * NDOFF * 4);
  int* cursor  = (int*)alloc((size_t)7 * NDOFF * 4);
  int* offsb   = (int*)alloc((size_t)7 * NDOFF * 4);
  int* src_csr = (int*)alloc((size_t)7 * EE * 4);
  float* ew_csr = (float*)alloc((size_t)7 * EE * 4);
  int* chunkS  = (int*)alloc((size_t)7 * NCHK * 4);
  int* chunkO  = (int*)alloc((size_t)7 * NCHK * 4);
  float* scal = (float*)alloc(256);
  if (off > ws_size) return;   // clean failure instead of fault if ws too small
  // Pcat (170000 x 256 bf16 = 87.04 MB) reuses comb+Qb+Kb+Vb (89.6 MB) after layers
  ushort_t* Pcat = comb;

  prep_scalars<<<1, 64, 0, stream>>>(theta, relimp, scal);
  transpose_weights<<<101, 256, 0, stream>>>(Wq, Wk, Wv, Wmsg, Wo, We1, Wt);
  transpose_wr1<<<32, 256, 0, stream>>>(Wr1, Wt + (size_t)101 * 16384);

  in_proj_all<<<2658, 256, 0, stream>>>(
      x[0], x[1], x[2], x[3], x[4], Win[0], Win[1], Win[2], Win[3], Win[4], b_in, h);

  // ---- CSR build (once; reused by all 3 layers) ----
  csr_clear<<<CDIV(7 * NDOFF, 256), 256, 0, stream>>>(counts);
  csr_hist<<<CDIV(7 * EE, 256), 256, 0, stream>>>(ei, counts);
  csr_chunk<<<7 * NCHK, 256, 0, stream>>>(counts, chunkS);
  csr_chunkscan<<<1, 64, 0, stream>>>(chunkS, chunkO);
  csr_scan_final<<<7 * NCHK, 1024, 0, stream>>>(counts, chunkO, offsb, cursor);
  csr_scatter<<<CDIV(7 * EE, 256), 256, 0, stream>>>(ei, ew, cursor, src_csr, ew_csr);

  for (int l = 0; l < 3; l++) {
    for (int r = 0; r < 7; r++) {
      int si = RSI[r], di = RDI[r];
      int nds = NCNT_[si], ndd = NCNT_[di];
      ushort_t* hs = h + (size_t)ROFF[si] * 128;
      ushort_t* hd = h + (size_t)ROFF[di] * 128;
      int lr = l * 7 + r;
      const ushort_t* WtQ = Wt + (size_t)lr * 16384;
      const ushort_t* WtK = Wt + (size_t)(21 + lr) * 16384;
      const ushort_t* WtV = Wt + (size_t)(42 + lr) * 16384;
      const ushort_t* WtM = Wt + (size_t)(63 + lr) * 16384;

      qkv_proj<<<CDIV(ndd, 64) + CDIV(nds, 64), 256, 0, stream>>>(
          hd, hs, WtQ, WtK, WtV, Qb, Kb, Vb, ndd, nds);
      ushort_t* cdst = comb + (size_t)ROFF[di] * 128;
      if (RFIRST[r])
        attn_msg<4><<<CDIV(ndd, 64), 256, 0, stream>>>(
            Qb, Kb, Vb, offsb + (size_t)r * NDOFF, src_csr + (size_t)r * EE,
            ew_csr + (size_t)r * EE, scal + r, WtM, cdst, ndd,
            scal + 8 + lr, bmsg + (size_t)lr * 128);
      else
        attn_msg<1><<<CDIV(ndd, 64), 256, 0, stream>>>(
            Qb, Kb, Vb, offsb + (size_t)r * NDOFF, src_csr + (size_t)r * EE,
            ew_csr + (size_t)r * EE, scal + r, WtM, cdst, ndd,
            scal + 8 + lr, bmsg + (size_t)lr * 128);
    }
    wo_ln_all<<<WO_TOTAL, 256, 0, stream>>>(h, comb, Wt, bo, lng, lnb, l);
  }

  // ---- heads ----
  gemm_pcat<<<CDIV(TOTROWS, 64), 256, 0, stream>>>(
      h, Wt + (size_t)99 * 16384, Wt + (size_t)100 * 16384, Pcat, TOTROWS);

  risk_mfma<<<CDIV(TOTROWS, 64), 256, 0, stream>>>(
      h, Wt + (size_t)101 * 16384, br1, Wr2, br2, out);

  edge_combine_all<<<7 * CDIV(EE, 4), 256, 0, stream>>>(Pcat, ei, be1, We2, be2, out);
}

// Round 8
// 1643.331 us; speedup vs baseline: 1.2173x; 1.2173x over previous
//
#include <hip/hip_runtime.h>

#define CDIV(a,b) (((a)+(b)-1)/(b))
#define EE 40000
#define TOTROWS 170000
#define NDOFF 60001
#define NCHK 59

typedef unsigned short ushort_t;
typedef short bf16x8 __attribute__((ext_vector_type(8)));
typedef float f32x4 __attribute__((ext_vector_type(4)));

__device__ __forceinline__ float eluf(float x) { return x > 0.f ? x : expm1f(x); }
__device__ __forceinline__ float sigf(float x) { return 1.f / (1.f + expf(-x)); }
__device__ __forceinline__ float b2f(ushort_t u) { return __uint_as_float(((unsigned)u) << 16); }
__device__ __forceinline__ ushort_t f2b(float f) {
  unsigned x = __float_as_uint(f);
  x += 0x7FFFu + ((x >> 16) & 1u);
  return (ushort_t)(x >> 16);
}
__device__ __forceinline__ unsigned pk2(float lo, float hi) {
  return (unsigned)f2b(lo) | ((unsigned)f2b(hi) << 16);
}
__device__ __forceinline__ float2 b2f2(unsigned u) {
  return make_float2(__uint_as_float(u << 16), __uint_as_float(u & 0xFFFF0000u));
}

__constant__ const int NDD_C[7] = {20000, 20000, 40000, 40000, 40000, 40000, 60000};

// ======== shared MFMA helpers ========
template<int BN>
__device__ __forceinline__ void stage_B(char* Bs, int tid, const ushort_t* Bt, const ushort_t* Bt2) {
#pragma unroll
  for (int i = 0; i < BN / 16; i++) {
    int u = tid + i * 256;
    int nrow = u >> 4;
    const ushort_t* sp = (BN == 256 && u >= 2048) ? (Bt2 + (size_t)(u - 2048) * 8)
                                                  : (Bt + (size_t)u * 8);
    uint4 w = *(const uint4*)sp;
    *(uint4*)(Bs + ((u * 16) ^ ((nrow & 7) << 4))) = w;
  }
}

__device__ __forceinline__ void stage_A_bf16(char* As, int tid, const ushort_t* Ab, int base, int n) {
#pragma unroll
  for (int i = 0; i < 4; i++) {
    int u = tid + i * 256;
    int row = u >> 4;
    int grow = base + row;
    uint4 v = make_uint4(0, 0, 0, 0);
    if (grow < n) v = *(const uint4*)&Ab[(size_t)grow * 128 + (u & 15) * 8];
    *(uint4*)(As + ((u * 16) ^ ((row & 7) << 4))) = v;
  }
}

template<int NF>
__device__ __forceinline__ void mfma_core(const char* As, const char* Bs, int lane, int wcol,
                                          f32x4 (&acc)[4][NF]) {
  int i16 = lane & 15, seg = lane >> 4;
#pragma unroll
  for (int s = 0; s < 4; s++) {
    bf16x8 a[4], b[NF];
#pragma unroll
    for (int m = 0; m < 4; m++) {
      int row = m * 16 + i16;
      a[m] = *(const bf16x8*)(As + ((row * 256 + s * 64 + seg * 16) ^ ((row & 7) << 4)));
    }
#pragma unroll
    for (int nn = 0; nn < NF; nn++) {
      int nr = wcol + nn * 16 + i16;
      b[nn] = *(const bf16x8*)(Bs + ((nr * 256 + s * 64 + seg * 16) ^ ((nr & 7) << 4)));
    }
#pragma unroll
    for (int m = 0; m < 4; m++)
#pragma unroll
      for (int nn = 0; nn < NF; nn++)
        acc[m][nn] = __builtin_amdgcn_mfma_f32_16x16x32_bf16(a[m], b[nn], acc[m][nn], 0, 0, 0);
  }
}

// ---------------- scalar prep
__global__ void prep_scalars(const float* __restrict__ theta, const float* __restrict__ rel_imp,
                             float* __restrict__ scal) {
  int t = threadIdx.x;
  if (t < 7) scal[t] = 1.f - sigf(theta[t]);
  if (t < 21) {
    const int partner[7] = {1, 0, 4, 5, 2, 3, -1};
    int l = t / 7, r = t % 7;
    float rw = sigf(rel_imp[t]);
    float w;
    if (partner[r] < 0) w = 1.f;
    else {
      float rwp = sigf(rel_imp[l * 7 + partner[r]]);
      float e0 = expf(rw), e1 = expf(rwp);
      w = e0 / (e0 + e1);
    }
    scal[8 + t] = w * rw;
  }
}

// ---------------- weight transpose + bf16 cast
__global__ __launch_bounds__(256) void transpose_weights(
    const float* __restrict__ Wq, const float* __restrict__ Wk, const float* __restrict__ Wv,
    const float* __restrict__ Wmsg, const float* __restrict__ Wo, const float* __restrict__ We1,
    ushort_t* __restrict__ Wt) {
  int mat = blockIdx.x;
  const float* src;
  if (mat < 21)      src = Wq   + (size_t)mat * 16384;
  else if (mat < 42) src = Wk   + (size_t)(mat - 21) * 16384;
  else if (mat < 63) src = Wv   + (size_t)(mat - 42) * 16384;
  else if (mat < 84) src = Wmsg + (size_t)(mat - 63) * 16384;
  else if (mat < 99) src = Wo   + (size_t)(mat - 84) * 16384;
  else               src = We1  + (size_t)(mat - 99) * 16384;
  __shared__ ushort_t lds[16384];
  int t = threadIdx.x;
  for (int i = 0; i < 64; i++) {
    int u = t + i * 256;            // u = k*128 + n
    int k = u >> 7;
    int byte = (u * 2) ^ ((k & 15) << 2);
    *(ushort_t*)((char*)lds + byte) = f2b(src[u]);
  }
  __syncthreads();
  ushort_t* dst = Wt + (size_t)mat * 16384;
  for (int i = 0; i < 64; i++) {
    int u = t + i * 256;            // u = n*128 + k
    int n = u >> 7, k = u & 127;
    int byte = ((k * 128 + n) * 2) ^ ((k & 15) << 2);
    dst[u] = *(ushort_t*)((char*)lds + byte);
  }
}

__global__ void transpose_wr1(const float* __restrict__ Wr1, ushort_t* __restrict__ Wt101) {
  int u = blockIdx.x * 256 + threadIdx.x;   // 8192
  int n = u >> 7, k = u & 127;
  Wt101[u] = f2b(Wr1[k * 64 + n]);
}

// ---------------- input projection: LDS-staged, templated-F, 64 rows/block
template<int F>
__device__ __forceinline__ void inproj_compute(const float* xs, const float* Ws, const float* b2,
                                               ushort_t* hptr, int base, int n, int tid) {
  int cp = tid & 63, rg = tid >> 6;
  float wc0[F], wc1[F];
#pragma unroll
  for (int f = 0; f < F; f++) {
    wc0[f] = Ws[f * 128 + cp * 2];
    wc1[f] = Ws[f * 128 + cp * 2 + 1];
  }
  float bb0 = b2[cp * 2], bb1 = b2[cp * 2 + 1];
  for (int i = 0; i < 16; i++) {
    int row = rg * 16 + i, grow = base + row;
    if (grow >= n) break;
    float a0 = bb0, a1 = bb1;
#pragma unroll
    for (int f = 0; f < F; f++) {
      float xv = xs[row * F + f];
      a0 = fmaf(xv, wc0[f], a0);
      a1 = fmaf(xv, wc1[f], a1);
    }
    *(unsigned*)&hptr[(size_t)grow * 128 + cp * 2] = pk2(eluf(a0), eluf(a1));
  }
}

__global__ __launch_bounds__(256) void in_proj_all(
    const float* __restrict__ x0, const float* __restrict__ x1, const float* __restrict__ x2,
    const float* __restrict__ x3, const float* __restrict__ x4,
    const float* __restrict__ W0, const float* __restrict__ W1, const float* __restrict__ W2,
    const float* __restrict__ W3, const float* __restrict__ W4,
    const float* __restrict__ b_in, ushort_t* __restrict__ h) {
  __shared__ float xs[64 * 22];
  __shared__ float Ws[22 * 128];
  int bb = blockIdx.x, tid = threadIdx.x;
  int ti, lb;
  if (bb < 938)       { ti = 0; lb = bb; }
  else if (bb < 1251) { ti = 1; lb = bb - 938; }
  else if (bb < 1876) { ti = 2; lb = bb - 1251; }
  else if (bb < 2501) { ti = 3; lb = bb - 1876; }
  else                { ti = 4; lb = bb - 2501; }
  const int ROFF_[5] = {0, 60000, 80000, 120000, 160000};
  const int NCNT_[5] = {60000, 20000, 40000, 40000, 10000};
  const int FEAT_[5] = {22, 6, 14, 5, 9};
  const float* xp = (ti == 0) ? x0 : (ti == 1) ? x1 : (ti == 2) ? x2 : (ti == 3) ? x3 : x4;
  const float* Wp = (ti == 0) ? W0 : (ti == 1) ? W1 : (ti == 2) ? W2 : (ti == 3) ? W3 : W4;
  int F = FEAT_[ti], n = NCNT_[ti], base = lb * 64;
  for (int u = tid; u < F * 128; u += 256) Ws[u] = Wp[u];
  for (int u = tid; u < 64 * F; u += 256) {
    int row = u / F, f = u - row * F, grow = base + row;
    xs[u] = (grow < n) ? xp[(size_t)grow * F + f] : 0.f;
  }
  __syncthreads();
  ushort_t* hptr = h + (size_t)ROFF_[ti] * 128;
  const float* b2 = b_in + ti * 128;
  switch (ti) {
    case 0: inproj_compute<22>(xs, Ws, b2, hptr, base, n, tid); break;
    case 1: inproj_compute<6>(xs, Ws, b2, hptr, base, n, tid); break;
    case 2: inproj_compute<14>(xs, Ws, b2, hptr, base, n, tid); break;
    case 3: inproj_compute<5>(xs, Ws, b2, hptr, base, n, tid); break;
    default: inproj_compute<9>(xs, Ws, b2, hptr, base, n, tid); break;
  }
}

// ================= CSR build (per relation, by dst) =================
__global__ void csr_clear(int* __restrict__ counts) {
  int idx = blockIdx.x * 256 + threadIdx.x;
  if (idx < 7 * NDOFF) counts[idx] = 0;
}

__global__ void csr_hist(const int* __restrict__ ei, int* __restrict__ counts) {
  int idx = blockIdx.x * 256 + threadIdx.x;
  if (idx >= 7 * EE) return;
  int r = idx / EE, e = idx - r * EE;
  int d = ei[(size_t)r * 2 * EE + EE + e];
  atomicAdd(&counts[r * NDOFF + d], 1);
}

__global__ __launch_bounds__(256) void csr_chunk(const int* __restrict__ counts, int* __restrict__ chunkSums) {
  int bb = blockIdx.x;                 // 7*NCHK
  int r = bb / NCHK, c = bb - r * NCHK;
  int ndd = NDD_C[r];
  int t = threadIdx.x;
  int v = 0;
#pragma unroll
  for (int j = 0; j < 4; j++) {
    int idx = c * 1024 + t + j * 256;
    if (idx < ndd) v += counts[r * NDOFF + idx];
  }
#pragma unroll
  for (int mm = 32; mm; mm >>= 1) v += __shfl_xor(v, mm);
  __shared__ int ws_[4];
  if ((t & 63) == 0) ws_[t >> 6] = v;
  __syncthreads();
  if (t == 0) chunkSums[bb] = ws_[0] + ws_[1] + ws_[2] + ws_[3];
}

__global__ void csr_chunkscan(const int* __restrict__ chunkSums, int* __restrict__ chunkOffs) {
  int r = threadIdx.x;
  if (r >= 7) return;
  int run = 0;
  for (int c = 0; c < NCHK; c++) {
    chunkOffs[r * NCHK + c] = run;
    run += chunkSums[r * NCHK + c];
  }
}

__global__ __launch_bounds__(1024) void csr_scan_final(
    const int* __restrict__ counts, const int* __restrict__ chunkOffs,
    int* __restrict__ offs, int* __restrict__ cursor) {
  int bb = blockIdx.x;
  int r = bb / NCHK, c = bb - r * NCHK;
  int ndd = NDD_C[r];
  int t = threadIdx.x;
  int idx = c * 1024 + t;
  int v = (idx < ndd) ? counts[r * NDOFF + idx] : 0;
  __shared__ int sc[1024];
  sc[t] = v;
  __syncthreads();
  for (int s = 1; s < 1024; s <<= 1) {
    int add = (t >= s) ? sc[t - s] : 0;
    __syncthreads();
    sc[t] += add;
    __syncthreads();
  }
  if (idx < ndd) {
    int excl = chunkOffs[r * NCHK + c] + sc[t] - v;
    offs[r * NDOFF + idx] = excl;
    cursor[r * NDOFF + idx] = excl;
  }
  if (t == 0 && c == 0) offs[r * NDOFF + ndd] = EE;
}

// scatter src + ew into CSR order
__global__ void csr_scatter(const int* __restrict__ ei, const float* __restrict__ ew,
                            int* __restrict__ cursor, int* __restrict__ src_csr,
                            float* __restrict__ ew_csr) {
  int idx = blockIdx.x * 256 + threadIdx.x;
  if (idx >= 7 * EE) return;
  int r = idx / EE, e = idx - r * EE;
  int d = ei[(size_t)r * 2 * EE + EE + e];
  int s = ei[(size_t)r * 2 * EE + e];
  int slot = atomicAdd(&cursor[r * NDOFF + d], 1);
  src_csr[r * EE + slot] = s;
  ew_csr[r * EE + slot] = ew[(size_t)r * EE + e];
}

// ---------------- fused QKV projections
__global__ __launch_bounds__(256) void qkv_proj(
    const ushort_t* __restrict__ hd, const ushort_t* __restrict__ hs,
    const ushort_t* __restrict__ WtQ, const ushort_t* __restrict__ WtK, const ushort_t* __restrict__ WtV,
    ushort_t* __restrict__ Qb, ushort_t* __restrict__ Kb, ushort_t* __restrict__ Vb,
    int ndd, int nds) {
  __shared__ char sm[16384 + 65536];
  char* As = sm;
  char* Bs = sm + 16384;
  int tid = threadIdx.x;
  int nqb = (ndd + 63) >> 6;
  int lane = tid & 63, wv = tid >> 6;
  int i16 = lane & 15, seg = lane >> 4;

  if ((int)blockIdx.x < nqb) {
    int base = blockIdx.x * 64;
    stage_B<128>(Bs, tid, WtQ, nullptr);
    stage_A_bf16(As, tid, hd, base, ndd);
    __syncthreads();
    f32x4 acc[4][2] = {};
    mfma_core<2>(As, Bs, lane, wv * 32, acc);
#pragma unroll
    for (int m = 0; m < 4; m++)
#pragma unroll
      for (int i = 0; i < 4; i++) {
        int grow = base + m * 16 + seg * 4 + i;
        if (grow >= ndd) continue;
#pragma unroll
        for (int nn = 0; nn < 2; nn++) {
          int col = wv * 32 + nn * 16 + i16;
          Qb[(size_t)grow * 128 + col] = f2b(acc[m][nn][i]);
        }
      }
  } else {
    int base = (blockIdx.x - nqb) * 64;
    stage_B<256>(Bs, tid, WtK, WtV);
    stage_A_bf16(As, tid, hs, base, nds);
    __syncthreads();
    f32x4 acc[4][4] = {};
    mfma_core<4>(As, Bs, lane, wv * 64, acc);
#pragma unroll
    for (int m = 0; m < 4; m++)
#pragma unroll
      for (int i = 0; i < 4; i++) {
        int grow = base + m * 16 + seg * 4 + i;
        if (grow >= nds) continue;
#pragma unroll
        for (int nn = 0; nn < 4; nn++) {
          int col = wv * 64 + nn * 16 + i16;
          ushort_t val = f2b(acc[m][nn][i]);
          if (col < 128) Kb[(size_t)grow * 128 + col] = val;
          else           Vb[(size_t)grow * 128 + col - 128] = val;
        }
      }
  }
}

// ---------------- CSR attention: one wave per dst node, packed CSR payload
__global__ __launch_bounds__(256) void attn_agg(
    const ushort_t* __restrict__ Qb, const ushort_t* __restrict__ Kb, const ushort_t* __restrict__ Vb,
    const int* __restrict__ offs, const int* __restrict__ src_csr, const float* __restrict__ ew_csr,
    const float* __restrict__ ews, ushort_t* __restrict__ Sb, float* __restrict__ degb, int ndd) {
  int node = blockIdx.x * 4 + (threadIdx.x >> 6);
  if (node >= ndd) return;
  int lane = threadIdx.x & 63;
  int beg = offs[node], end = offs[node + 1];
  float escale = ews[0] * 0.17677669529663687f;
  float q0 = b2f(Qb[(size_t)node * 128 + lane]);
  float q1 = b2f(Qb[(size_t)node * 128 + 64 + lane]);
  float m0 = -3.0e38f, m1 = -3.0e38f, z0 = 0.f, z1 = 0.f, a0 = 0.f, a1 = 0.f;
  for (int p = beg; p < end; p++) {
    int s = src_csr[p];
    float wgt = ew_csr[p] * escale;
    float k0 = b2f(Kb[(size_t)s * 128 + lane]);
    float k1 = b2f(Kb[(size_t)s * 128 + 64 + lane]);
    float p0 = q0 * k0, p1 = q1 * k1;
#pragma unroll
    for (int mm = 16; mm; mm >>= 1) {
      p0 += __shfl_xor(p0, mm);
      p1 += __shfl_xor(p1, mm);
    }
    float s0 = p0 * wgt, s1 = p1 * wgt;
    float nm0 = fmaxf(m0, s0), nm1 = fmaxf(m1, s1);
    float r0 = expf(m0 - nm0), r1 = expf(m1 - nm1);
    float e0 = expf(s0 - nm0), e1 = expf(s1 - nm1);
    float v0 = b2f(Vb[(size_t)s * 128 + lane]);
    float v1 = b2f(Vb[(size_t)s * 128 + 64 + lane]);
    z0 = z0 * r0 + e0; a0 = a0 * r0 + e0 * v0; m0 = nm0;
    z1 = z1 * r1 + e1; a1 = a1 * r1 + e1 * v1; m1 = nm1;
  }
  Sb[(size_t)node * 128 + lane]      = f2b(a0 / (z0 + 1e-10f));
  Sb[(size_t)node * 128 + 64 + lane] = f2b(a1 / (z1 + 1e-10f));
  if (lane == 0) degb[node] = (float)(end - beg);
}

// ---------------- MFMA GEMM (msg accumulate); A bf16 (normalized S)
// MODE 1: comb += coef*(acc + deg*bmsg); MODE 4: comb = ...
template<int MODE>
__global__ __launch_bounds__(256) void gemm_msg(
    const ushort_t* __restrict__ Ap, const ushort_t* __restrict__ Bt,
    ushort_t* __restrict__ C1, int n,
    const float* __restrict__ coefp, const float* __restrict__ deg, const float* __restrict__ bvec) {
  __shared__ char sm[16384 + 32768];
  char* As = sm;
  char* Bs = sm + 16384;
  int tid = threadIdx.x;
  int base = blockIdx.x * 64;
  stage_B<128>(Bs, tid, Bt, nullptr);
  stage_A_bf16(As, tid, Ap, base, n);
  __syncthreads();
  int lane = tid & 63, wv = tid >> 6;
  int i16 = lane & 15, seg = lane >> 4;
  f32x4 acc[4][2] = {};
  mfma_core<2>(As, Bs, lane, wv * 32, acc);
  float coef = *coefp;
#pragma unroll
  for (int m = 0; m < 4; m++)
#pragma unroll
    for (int i = 0; i < 4; i++) {
      int grow = base + m * 16 + seg * 4 + i;
      if (grow >= n) continue;
      float dg = deg[grow];
#pragma unroll
      for (int nn = 0; nn < 2; nn++) {
        int col = wv * 32 + nn * 16 + i16;
        ushort_t* cp = &C1[(size_t)grow * 128 + col];
        float mv = coef * (acc[m][nn][i] + dg * bvec[col]);
        if (MODE == 1) mv += b2f(*cp);
        *cp = f2b(mv);
      }
    }
}

// ---------------- Pcat GEMM (BN=256, split weights)
__global__ __launch_bounds__(256) void gemm_pcat(
    const ushort_t* __restrict__ Ap, const ushort_t* __restrict__ Bt, const ushort_t* __restrict__ Bt2,
    ushort_t* __restrict__ C1, int n) {
  __shared__ char sm[16384 + 65536];
  char* As = sm;
  char* Bs = sm + 16384;
  int tid = threadIdx.x;
  int base = blockIdx.x * 64;
  stage_B<256>(Bs, tid, Bt, Bt2);
  stage_A_bf16(As, tid, Ap, base, n);
  __syncthreads();
  int lane = tid & 63, wv = tid >> 6;
  int i16 = lane & 15, seg = lane >> 4;
  f32x4 acc[4][4] = {};
  mfma_core<4>(As, Bs, lane, wv * 64, acc);
#pragma unroll
  for (int m = 0; m < 4; m++)
#pragma unroll
    for (int i = 0; i < 4; i++) {
      int grow = base + m * 16 + seg * 4 + i;
      if (grow >= n) continue;
#pragma unroll
      for (int nn = 0; nn < 4; nn++) {
        int col = wv * 64 + nn * 16 + i16;
        C1[(size_t)grow * 256 + col] = f2b(acc[m][nn][i]);
      }
    }
}

// ---------------- batched Wo GEMM + residual + LN + elu, + AIAgent elu tail
// Ys stride 132 floats (banks shift 4/row -> conflict-free staging)
#define WO_C1 938
#define WO_C2 1251
#define WO_C3 1876
#define WO_C4 2501
#define WO_TOTAL 2814
#define YSTR 132
__global__ __launch_bounds__(256) void wo_ln_all(
    ushort_t* __restrict__ h, const ushort_t* __restrict__ comb, const ushort_t* __restrict__ Wt,
    const float* __restrict__ bo, const float* __restrict__ lng, const float* __restrict__ lnb, int l) {
  int bb = blockIdx.x;
  int tid = threadIdx.x;
  if (bb >= WO_C4) {
    int idx16 = (bb - WO_C4) * 256 + tid;
    if (idx16 >= 80000) return;
    ushort_t* p = h + (size_t)160000 * 128 + (size_t)idx16 * 16;
    uint4 v0 = *(uint4*)p, v1 = *(uint4*)(p + 8);
    unsigned* u0 = (unsigned*)&v0;
    unsigned* u1 = (unsigned*)&v1;
#pragma unroll
    for (int i = 0; i < 4; i++) {
      float2 a = b2f2(u0[i]); u0[i] = pk2(eluf(a.x), eluf(a.y));
      float2 b = b2f2(u1[i]); u1[i] = pk2(eluf(b.x), eluf(b.y));
    }
    *(uint4*)p = v0; *(uint4*)(p + 8) = v1;
    return;
  }
  int ti, lb;
  if (bb < WO_C1)      { ti = 0; lb = bb; }
  else if (bb < WO_C2) { ti = 1; lb = bb - WO_C1; }
  else if (bb < WO_C3) { ti = 2; lb = bb - WO_C2; }
  else                 { ti = 3; lb = bb - WO_C3; }
  const int ROFF_[4] = {0, 60000, 80000, 120000};
  const int NCNT4_[4] = {60000, 20000, 40000, 40000};
  int n = NCNT4_[ti];
  int base = lb * 64;
  int li = l * 5 + ti;
  const ushort_t* A = comb + (size_t)ROFF_[ti] * 128;
  ushort_t* C1 = h + (size_t)ROFF_[ti] * 128;
  const ushort_t* Bt = Wt + (size_t)(84 + li) * 16384;
  const float* bvec = bo + (size_t)li * 128;
  const float* g = lng + (size_t)li * 128;
  const float* b = lnb + (size_t)li * 128;

  __shared__ char sm[16384 + 34048];   // As 16K + max(Bs 32K, Ys 64*132*4=33792)
  char* As = sm;
  char* Bs = sm + 16384;
  stage_B<128>(Bs, tid, Bt, nullptr);
  stage_A_bf16(As, tid, A, base, n);
  __syncthreads();
  int lane = tid & 63, wv = tid >> 6;
  int i16 = lane & 15, seg = lane >> 4;
  f32x4 acc[4][2] = {};
  mfma_core<2>(As, Bs, lane, wv * 32, acc);

  __syncthreads();
  float* Ys = (float*)sm;    // overlays As+Bs (both dead now)
#pragma unroll
  for (int m = 0; m < 4; m++)
#pragma unroll
    for (int i = 0; i < 4; i++) {
      int rl = m * 16 + seg * 4 + i;
      int grow = base + rl;
      if (grow >= n) continue;
#pragma unroll
      for (int nn = 0; nn < 2; nn++) {
        int col = wv * 32 + nn * 16 + i16;
        Ys[rl * YSTR + col] = acc[m][nn][i] + b2f(C1[(size_t)grow * 128 + col]) + bvec[col];
      }
    }
  __syncthreads();
  for (int rr = 0; rr < 16; rr++) {
    int rl = wv * 16 + rr;
    int grow = base + rl;
    if (grow >= n) continue;
    float y0 = Ys[rl * YSTR + lane], y1 = Ys[rl * YSTR + 64 + lane];
    float sum = y0 + y1;
#pragma unroll
    for (int mm = 32; mm; mm >>= 1) sum += __shfl_xor(sum, mm);
    float mu = sum * (1.f / 128.f);
    float d0 = y0 - mu, d1 = y1 - mu;
    float vs = d0 * d0 + d1 * d1;
#pragma unroll
    for (int mm = 32; mm; mm >>= 1) vs += __shfl_xor(vs, mm);
    float rs = rsqrtf(vs * (1.f / 128.f) + 1e-5f);
    C1[(size_t)grow * 128 + lane]      = f2b(eluf(d0 * rs * g[lane] + b[lane]));
    C1[(size_t)grow * 128 + 64 + lane] = f2b(eluf(d1 * rs * g[64 + lane] + b[64 + lane]));
  }
}

// ---------------- MFMA risk head
__global__ __launch_bounds__(256) void risk_mfma(
    const ushort_t* __restrict__ Hh, const ushort_t* __restrict__ Wt101,
    const float* __restrict__ br1, const float* __restrict__ Wr2, const float* __restrict__ br2,
    float* __restrict__ out) {
  __shared__ char sm[16384 + 16384 + 64 * 68 * 4];
  char* As = sm;
  char* Bs = sm + 16384;
  float* Hs = (float*)(sm + 32768);
  int tid = threadIdx.x;
  int base = blockIdx.x * 64;
#pragma unroll
  for (int i = 0; i < 4; i++) {
    int u = tid + i * 256;
    int nrow = u >> 4;
    uint4 w = *(const uint4*)(Wt101 + (size_t)u * 8);
    *(uint4*)(Bs + ((u * 16) ^ ((nrow & 7) << 4))) = w;
  }
  stage_A_bf16(As, tid, Hh, base, TOTROWS);
  __syncthreads();
  int lane = tid & 63, wv = tid >> 6;
  int i16 = lane & 15, seg = lane >> 4;
  f32x4 acc[4][1] = {};
  mfma_core<1>(As, Bs, lane, wv * 16, acc);
#pragma unroll
  for (int m = 0; m < 4; m++)
#pragma unroll
    for (int i = 0; i < 4; i++) {
      int rl = m * 16 + seg * 4 + i;
      int col = wv * 16 + i16;
      Hs[rl * 68 + col] = eluf(acc[m][0][i] + br1[col]);
    }
  __syncthreads();
  float wr2r = Wr2[lane];
  for (int rr = 0; rr < 16; rr++) {
    int rl = wv * 16 + rr;
    int grow = base + rl;
    float v = Hs[rl * 68 + lane] * wr2r;
#pragma unroll
    for (int mm = 32; mm; mm >>= 1) v += __shfl_xor(v, mm);
    if (lane == 0 && grow < TOTROWS) out[grow] = sigf(v + br2[0]);
  }
}

// ---------------- batched edge heads
__global__ __launch_bounds__(256) void edge_combine_all(
    const ushort_t* __restrict__ Pcat, const int* __restrict__ ei,
    const float* __restrict__ be1, const float* __restrict__ We2,
    const float* __restrict__ be2, float* __restrict__ out) {
  const int RSI_[7] = {0, 1, 0, 0, 2, 4, 0};
  const int RDI_[7] = {1, 1, 2, 3, 2, 3, 0};
  const int ROFF_[5] = {0, 60000, 80000, 120000, 160000};
  int bb = blockIdx.x;
  int r = bb / 10000;
  int lane = threadIdx.x & 63;
  int e = (bb % 10000) * 4 + (threadIdx.x >> 6);
  const int* src = ei + (size_t)r * 2 * EE;
  const int* dst = src + EE;
  int s = src[e], d = dst[e];
  const ushort_t* p1 = Pcat + ((size_t)(ROFF_[RSI_[r]] + s)) * 256;
  const ushort_t* p2 = Pcat + ((size_t)(ROFF_[RDI_[r]] + d)) * 256 + 128;
  float h0 = eluf(b2f(p1[lane])      + b2f(p2[lane])      + be1[lane]);
  float h1 = eluf(b2f(p1[64 + lane]) + b2f(p2[64 + lane]) + be1[64 + lane]);
  float v = h0 * We2[lane] + h1 * We2[64 + lane];
#pragma unroll
  for (int mm = 32; mm; mm >>= 1) v += __shfl_xor(v, mm);
  if (lane == 0) out[TOTROWS + (size_t)r * EE + e] = sigf(v + be2[0]);
}

extern "C" void kernel_launch(void* const* d_in, const int* in_sizes, int n_in,
                              void* d_out, int out_size, void* d_ws, size_t ws_size,
                              hipStream_t stream) {
  (void)in_sizes; (void)n_in; (void)out_size;
  static const int NCNT_[5] = {60000, 20000, 40000, 40000, 10000};
  static const int RSI[7] = {0, 1, 0, 0, 2, 4, 0};
  static const int RDI[7] = {1, 1, 2, 3, 2, 3, 0};
  static const int RFIRST[7] = {1, 0, 1, 1, 0, 0, 1};
  static const int ROFF[5] = {0, 60000, 80000, 120000, 160000};

  const float* x[5];    for (int i = 0; i < 5; i++) x[i] = (const float*)d_in[i];
  const int*   ei     = (const int*)d_in[5];
  const float* ew     = (const float*)d_in[6];
  const float* theta  = (const float*)d_in[7];
  const float* Win[5]; for (int i = 0; i < 5; i++) Win[i] = (const float*)d_in[8 + i];
  const float* b_in   = (const float*)d_in[13];
  const float* Wq     = (const float*)d_in[14];
  const float* Wk     = (const float*)d_in[15];
  const float* Wv     = (const float*)d_in[16];
  const float* Wmsg   = (const float*)d_in[17];
  const float* bmsg   = (const float*)d_in[18];
  const float* relimp = (const float*)d_in[19];
  const float* Wo     = (const float*)d_in[20];
  const float* bo     = (const float*)d_in[21];
  const float* lng    = (const float*)d_in[22];
  const float* lnb    = (const float*)d_in[23];
  const float* Wr1    = (const float*)d_in[24];
  const float* br1    = (const float*)d_in[25];
  const float* Wr2    = (const float*)d_in[26];
  const float* br2    = (const float*)d_in[27];
  const float* We1    = (const float*)d_in[28];
  const float* be1    = (const float*)d_in[29];
  const float* We2    = (const float*)d_in[30];
  const float* be2    = (const float*)d_in[31];
  float* out = (float*)d_out;

  // ---- workspace ----
  char* ws = (char*)d_ws;
  size_t off = 0;
  auto alloc = [&](size_t bytes) -> void* {
    void* p = (void*)(ws + off);
    off = (off + bytes + 255) & ~(size_t)255;
    return p;
  };
  ushort_t* h    = (ushort_t*)alloc((size_t)TOTROWS * 128 * 2);
  ushort_t* comb = (ushort_t*)alloc((size_t)TOTROWS * 128 * 2);
  ushort_t* Qb   = (ushort_t*)alloc((size_t)60000 * 128 * 2);
  ushort_t* Kb   = (ushort_t*)alloc((size_t)60000 * 128 * 2);
  ushort_t* Vb   = (ushort_t*)alloc((size_t)60000 * 128 * 2);
  ushort_t* Sb   = (ushort_t*)alloc((size_t)60000 * 128 * 2);
  float* degb = (float*)alloc((size_t)60000 * 4);
  ushort_t* Wt = (ushort_t*)alloc((size_t)102 * 16384 * 2);
  int* counts  = (int*)alloc((size_t)7 * NDOFF * 4);
  int* cursor  = (int*)alloc((size_t)7 * NDOFF * 4);
  int* offsb   = (int*)alloc((size_t)7 * NDOFF * 4);
  int* src_csr = (int*)alloc((size_t)7 * EE * 4);
  float* ew_csr = (float*)alloc((size_t)7 * EE * 4);
  int* chunkS  = (int*)alloc((size_t)7 * NCHK * 4);
  int* chunkO  = (int*)alloc((size_t)7 * NCHK * 4);
  float* scal = (float*)alloc(256);
  if (off > ws_size) return;   // clean failure instead of fault if ws too small
  ushort_t* Pcat = comb;       // reuse after layers

  prep_scalars<<<1, 64, 0, stream>>>(theta, relimp, scal);
  transpose_weights<<<101, 256, 0, stream>>>(Wq, Wk, Wv, Wmsg, Wo, We1, Wt);
  transpose_wr1<<<32, 256, 0, stream>>>(Wr1, Wt + (size_t)101 * 16384);

  in_proj_all<<<2658, 256, 0, stream>>>(
      x[0], x[1], x[2], x[3], x[4], Win[0], Win[1], Win[2], Win[3], Win[4], b_in, h);

  // ---- CSR build (once; reused by all 3 layers) ----
  csr_clear<<<CDIV(7 * NDOFF, 256), 256, 0, stream>>>(counts);
  csr_hist<<<CDIV(7 * EE, 256), 256, 0, stream>>>(ei, counts);
  csr_chunk<<<7 * NCHK, 256, 0, stream>>>(counts, chunkS);
  csr_chunkscan<<<1, 64, 0, stream>>>(chunkS, chunkO);
  csr_scan_final<<<7 * NCHK, 1024, 0, stream>>>(counts, chunkO, offsb, cursor);
  csr_scatter<<<CDIV(7 * EE, 256), 256, 0, stream>>>(ei, ew, cursor, src_csr, ew_csr);

  for (int l = 0; l < 3; l++) {
    for (int r = 0; r < 7; r++) {
      int si = RSI[r], di = RDI[r];
      int nds = NCNT_[si], ndd = NCNT_[di];
      ushort_t* hs = h + (size_t)ROFF[si] * 128;
      ushort_t* hd = h + (size_t)ROFF[di] * 128;
      int lr = l * 7 + r;
      const ushort_t* WtQ = Wt + (size_t)lr * 16384;
      const ushort_t* WtK = Wt + (size_t)(21 + lr) * 16384;
      const ushort_t* WtV = Wt + (size_t)(42 + lr) * 16384;
      const ushort_t* WtM = Wt + (size_t)(63 + lr) * 16384;

      qkv_proj<<<CDIV(ndd, 64) + CDIV(nds, 64), 256, 0, stream>>>(
          hd, hs, WtQ, WtK, WtV, Qb, Kb, Vb, ndd, nds);
      attn_agg<<<CDIV(ndd, 4), 256, 0, stream>>>(
          Qb, Kb, Vb, offsb + (size_t)r * NDOFF, src_csr + (size_t)r * EE,
          ew_csr + (size_t)r * EE, scal + r, Sb, degb, ndd);
      ushort_t* cdst = comb + (size_t)ROFF[di] * 128;
      if (RFIRST[r])
        gemm_msg<4><<<CDIV(ndd, 64), 256, 0, stream>>>(
            Sb, WtM, cdst, ndd, scal + 8 + lr, degb, bmsg + (size_t)lr * 128);
      else
        gemm_msg<1><<<CDIV(ndd, 64), 256, 0, stream>>>(
            Sb, WtM, cdst, ndd, scal + 8 + lr, degb, bmsg + (size_t)lr * 128);
    }
    wo_ln_all<<<WO_TOTAL, 256, 0, stream>>>(h, comb, Wt, bo, lng, lnb, l);
  }

  // ---- heads ----
  gemm_pcat<<<CDIV(TOTROWS, 64), 256, 0, stream>>>(
      h, Wt + (size_t)99 * 16384, Wt + (size_t)100 * 16384, Pcat, TOTROWS);

  risk_mfma<<<CDIV(TOTROWS, 64), 256, 0, stream>>>(
      h, Wt + (size_t)101 * 16384, br1, Wr2, br2, out);

  edge_combine_all<<<7 * CDIV(EE, 4), 256, 0, stream>>>(Pcat, ei, be1, We2, be2, out);
}

// Round 10
// 1610.236 us; speedup vs baseline: 1.2424x; 1.0206x over previous
//
#include <hip/hip_runtime.h>

#define CDIV(a,b) (((a)+(b)-1)/(b))
#define EE 40000
#define TOTROWS 170000
#define NDOFF 60001
#define NCHK 59
#define G_PCAT 2657

typedef unsigned short ushort_t;
typedef short bf16x8 __attribute__((ext_vector_type(8)));
typedef float f32x4 __attribute__((ext_vector_type(4)));

__device__ __forceinline__ float eluf(float x) { return x > 0.f ? x : expm1f(x); }
__device__ __forceinline__ float sigf(float x) { return 1.f / (1.f + expf(-x)); }
__device__ __forceinline__ float b2f(ushort_t u) { return __uint_as_float(((unsigned)u) << 16); }
__device__ __forceinline__ ushort_t f2b(float f) {
  unsigned x = __float_as_uint(f);
  x += 0x7FFFu + ((x >> 16) & 1u);
  return (ushort_t)(x >> 16);
}
__device__ __forceinline__ unsigned pk2(float lo, float hi) {
  return (unsigned)f2b(lo) | ((unsigned)f2b(hi) << 16);
}
__device__ __forceinline__ float2 b2f2(unsigned u) {
  return make_float2(__uint_as_float(u << 16), __uint_as_float(u & 0xFFFF0000u));
}

__constant__ const int NDD_C[7] = {20000, 20000, 40000, 40000, 40000, 40000, 60000};

// ======== shared MFMA helpers ========
template<int BN>
__device__ __forceinline__ void stage_B(char* Bs, int tid, const ushort_t* Bt, const ushort_t* Bt2) {
#pragma unroll
  for (int i = 0; i < BN / 16; i++) {
    int u = tid + i * 256;
    int nrow = u >> 4;
    const ushort_t* sp = (BN == 256 && u >= 2048) ? (Bt2 + (size_t)(u - 2048) * 8)
                                                  : (Bt + (size_t)u * 8);
    uint4 w = *(const uint4*)sp;
    *(uint4*)(Bs + ((u * 16) ^ ((nrow & 7) << 4))) = w;
  }
}

__device__ __forceinline__ void stage_A_bf16(char* As, int tid, const ushort_t* Ab, int base, int n) {
#pragma unroll
  for (int i = 0; i < 4; i++) {
    int u = tid + i * 256;
    int row = u >> 4;
    int grow = base + row;
    uint4 v = make_uint4(0, 0, 0, 0);
    if (grow < n) v = *(const uint4*)&Ab[(size_t)grow * 128 + (u & 15) * 8];
    *(uint4*)(As + ((u * 16) ^ ((row & 7) << 4))) = v;
  }
}

template<int NF>
__device__ __forceinline__ void mfma_core(const char* As, const char* Bs, int lane, int wcol,
                                          f32x4 (&acc)[4][NF]) {
  int i16 = lane & 15, seg = lane >> 4;
#pragma unroll
  for (int s = 0; s < 4; s++) {
    bf16x8 a[4], b[NF];
#pragma unroll
    for (int m = 0; m < 4; m++) {
      int row = m * 16 + i16;
      a[m] = *(const bf16x8*)(As + ((row * 256 + s * 64 + seg * 16) ^ ((row & 7) << 4)));
    }
#pragma unroll
    for (int nn = 0; nn < NF; nn++) {
      int nr = wcol + nn * 16 + i16;
      b[nn] = *(const bf16x8*)(Bs + ((nr * 256 + s * 64 + seg * 16) ^ ((nr & 7) << 4)));
    }
#pragma unroll
    for (int m = 0; m < 4; m++)
#pragma unroll
      for (int nn = 0; nn < NF; nn++)
        acc[m][nn] = __builtin_amdgcn_mfma_f32_16x16x32_bf16(a[m], b[nn], acc[m][nn], 0, 0, 0);
  }
}

// ---------------- scalar prep
__global__ void prep_scalars(const float* __restrict__ theta, const float* __restrict__ rel_imp,
                             float* __restrict__ scal) {
  int t = threadIdx.x;
  if (t < 7) scal[t] = 1.f - sigf(theta[t]);
  if (t < 21) {
    const int partner[7] = {1, 0, 4, 5, 2, 3, -1};
    int l = t / 7, r = t % 7;
    float rw = sigf(rel_imp[t]);
    float w;
    if (partner[r] < 0) w = 1.f;
    else {
      float rwp = sigf(rel_imp[l * 7 + partner[r]]);
      float e0 = expf(rw), e1 = expf(rwp);
      w = e0 / (e0 + e1);
    }
    scal[8 + t] = w * rw;
  }
}

// ---------------- weight transpose + bf16 cast
__global__ __launch_bounds__(256) void transpose_weights(
    const float* __restrict__ Wq, const float* __restrict__ Wk, const float* __restrict__ Wv,
    const float* __restrict__ Wmsg, const float* __restrict__ Wo, const float* __restrict__ We1,
    ushort_t* __restrict__ Wt) {
  int mat = blockIdx.x;
  const float* src;
  if (mat < 21)      src = Wq   + (size_t)mat * 16384;
  else if (mat < 42) src = Wk   + (size_t)(mat - 21) * 16384;
  else if (mat < 63) src = Wv   + (size_t)(mat - 42) * 16384;
  else if (mat < 84) src = Wmsg + (size_t)(mat - 63) * 16384;
  else if (mat < 99) src = Wo   + (size_t)(mat - 84) * 16384;
  else               src = We1  + (size_t)(mat - 99) * 16384;
  __shared__ ushort_t lds[16384];
  int t = threadIdx.x;
  for (int i = 0; i < 64; i++) {
    int u = t + i * 256;            // u = k*128 + n
    int k = u >> 7;
    int byte = (u * 2) ^ ((k & 15) << 2);
    *(ushort_t*)((char*)lds + byte) = f2b(src[u]);
  }
  __syncthreads();
  ushort_t* dst = Wt + (size_t)mat * 16384;
  for (int i = 0; i < 64; i++) {
    int u = t + i * 256;            // u = n*128 + k
    int n = u >> 7, k = u & 127;
    int byte = ((k * 128 + n) * 2) ^ ((k & 15) << 2);
    dst[u] = *(ushort_t*)((char*)lds + byte);
  }
}

__global__ void transpose_wr1(const float* __restrict__ Wr1, ushort_t* __restrict__ Wt101) {
  int u = blockIdx.x * 256 + threadIdx.x;   // 8192
  int n = u >> 7, k = u & 127;
  Wt101[u] = f2b(Wr1[k * 64 + n]);
}

// ---------------- input projection: LDS-staged, templated-F, 64 rows/block
template<int F>
__device__ __forceinline__ void inproj_compute(const float* xs, const float* Ws, const float* b2,
                                               ushort_t* hptr, int base, int n, int tid) {
  int cp = tid & 63, rg = tid >> 6;
  float wc0[F], wc1[F];
#pragma unroll
  for (int f = 0; f < F; f++) {
    wc0[f] = Ws[f * 128 + cp * 2];
    wc1[f] = Ws[f * 128 + cp * 2 + 1];
  }
  float bb0 = b2[cp * 2], bb1 = b2[cp * 2 + 1];
  for (int i = 0; i < 16; i++) {
    int row = rg * 16 + i, grow = base + row;
    if (grow >= n) break;
    float a0 = bb0, a1 = bb1;
#pragma unroll
    for (int f = 0; f < F; f++) {
      float xv = xs[row * F + f];
      a0 = fmaf(xv, wc0[f], a0);
      a1 = fmaf(xv, wc1[f], a1);
    }
    *(unsigned*)&hptr[(size_t)grow * 128 + cp * 2] = pk2(eluf(a0), eluf(a1));
  }
}

__global__ __launch_bounds__(256) void in_proj_all(
    const float* __restrict__ x0, const float* __restrict__ x1, const float* __restrict__ x2,
    const float* __restrict__ x3, const float* __restrict__ x4,
    const float* __restrict__ W0, const float* __restrict__ W1, const float* __restrict__ W2,
    const float* __restrict__ W3, const float* __restrict__ W4,
    const float* __restrict__ b_in, ushort_t* __restrict__ h) {
  __shared__ float xs[64 * 22];
  __shared__ float Ws[22 * 128];
  int bb = blockIdx.x, tid = threadIdx.x;
  int ti, lb;
  if (bb < 938)       { ti = 0; lb = bb; }
  else if (bb < 1251) { ti = 1; lb = bb - 938; }
  else if (bb < 1876) { ti = 2; lb = bb - 1251; }
  else if (bb < 2501) { ti = 3; lb = bb - 1876; }
  else                { ti = 4; lb = bb - 2501; }
  const int ROFF_[5] = {0, 60000, 80000, 120000, 160000};
  const int NCNT_[5] = {60000, 20000, 40000, 40000, 10000};
  const int FEAT_[5] = {22, 6, 14, 5, 9};
  const float* xp = (ti == 0) ? x0 : (ti == 1) ? x1 : (ti == 2) ? x2 : (ti == 3) ? x3 : x4;
  const float* Wp = (ti == 0) ? W0 : (ti == 1) ? W1 : (ti == 2) ? W2 : (ti == 3) ? W3 : W4;
  int F = FEAT_[ti], n = NCNT_[ti], base = lb * 64;
  for (int u = tid; u < F * 128; u += 256) Ws[u] = Wp[u];
  for (int u = tid; u < 64 * F; u += 256) {
    int row = u / F, f = u - row * F, grow = base + row;
    xs[u] = (grow < n) ? xp[(size_t)grow * F + f] : 0.f;
  }
  __syncthreads();
  ushort_t* hptr = h + (size_t)ROFF_[ti] * 128;
  const float* b2 = b_in + ti * 128;
  switch (ti) {
    case 0: inproj_compute<22>(xs, Ws, b2, hptr, base, n, tid); break;
    case 1: inproj_compute<6>(xs, Ws, b2, hptr, base, n, tid); break;
    case 2: inproj_compute<14>(xs, Ws, b2, hptr, base, n, tid); break;
    case 3: inproj_compute<5>(xs, Ws, b2, hptr, base, n, tid); break;
    default: inproj_compute<9>(xs, Ws, b2, hptr, base, n, tid); break;
  }
}

// ================= CSR build =================
__global__ void csr_clear(int* __restrict__ counts) {
  int idx = blockIdx.x * 256 + threadIdx.x;
  if (idx < 7 * NDOFF) counts[idx] = 0;
}

__global__ void csr_hist(const int* __restrict__ ei, int* __restrict__ counts) {
  int idx = blockIdx.x * 256 + threadIdx.x;
  if (idx >= 7 * EE) return;
  int r = idx / EE, e = idx - r * EE;
  int d = ei[(size_t)r * 2 * EE + EE + e];
  atomicAdd(&counts[r * NDOFF + d], 1);
}

__global__ __launch_bounds__(256) void csr_chunk(const int* __restrict__ counts, int* __restrict__ chunkSums) {
  int bb = blockIdx.x;
  int r = bb / NCHK, c = bb - r * NCHK;
  int ndd = NDD_C[r];
  int t = threadIdx.x;
  int v = 0;
#pragma unroll
  for (int j = 0; j < 4; j++) {
    int idx = c * 1024 + t + j * 256;
    if (idx < ndd) v += counts[r * NDOFF + idx];
  }
#pragma unroll
  for (int mm = 32; mm; mm >>= 1) v += __shfl_xor(v, mm);
  __shared__ int ws_[4];
  if ((t & 63) == 0) ws_[t >> 6] = v;
  __syncthreads();
  if (t == 0) chunkSums[bb] = ws_[0] + ws_[1] + ws_[2] + ws_[3];
}

__global__ void csr_chunkscan(const int* __restrict__ chunkSums, int* __restrict__ chunkOffs) {
  int r = threadIdx.x;
  if (r >= 7) return;
  int run = 0;
  for (int c = 0; c < NCHK; c++) {
    chunkOffs[r * NCHK + c] = run;
    run += chunkSums[r * NCHK + c];
  }
}

__global__ __launch_bounds__(1024) void csr_scan_final(
    const int* __restrict__ counts, const int* __restrict__ chunkOffs,
    int* __restrict__ offs, int* __restrict__ cursor) {
  int bb = blockIdx.x;
  int r = bb / NCHK, c = bb - r * NCHK;
  int ndd = NDD_C[r];
  int t = threadIdx.x;
  int idx = c * 1024 + t;
  int v = (idx < ndd) ? counts[r * NDOFF + idx] : 0;
  __shared__ int sc[1024];
  sc[t] = v;
  __syncthreads();
  for (int s = 1; s < 1024; s <<= 1) {
    int add = (t >= s) ? sc[t - s] : 0;
    __syncthreads();
    sc[t] += add;
    __syncthreads();
  }
  if (idx < ndd) {
    int excl = chunkOffs[r * NCHK + c] + sc[t] - v;
    offs[r * NDOFF + idx] = excl;
    cursor[r * NDOFF + idx] = excl;
  }
  if (t == 0 && c == 0) offs[r * NDOFF + ndd] = EE;
}

__global__ void csr_scatter(const int* __restrict__ ei, const float* __restrict__ ew,
                            int* __restrict__ cursor, int* __restrict__ src_csr,
                            float* __restrict__ ew_csr) {
  int idx = blockIdx.x * 256 + threadIdx.x;
  if (idx >= 7 * EE) return;
  int r = idx / EE, e = idx - r * EE;
  int d = ei[(size_t)r * 2 * EE + EE + e];
  int s = ei[(size_t)r * 2 * EE + e];
  int slot = atomicAdd(&cursor[r * NDOFF + d], 1);
  src_csr[r * EE + slot] = s;
  ew_csr[r * EE + slot] = ew[(size_t)r * EE + e];
}

// ---------------- fused launch: msg-GEMM (prev relation) + QKV (current relation)
// blocks [0,gmsg): comb (+)= coef*(Sb@WtM + deg*bmsg); blocks [gmsg, gmsg+gq+gkv): QKV proj
template<int MODE>
__global__ __launch_bounds__(256) void msg_qkv(
    const ushort_t* __restrict__ Sb, const ushort_t* __restrict__ WtM,
    ushort_t* __restrict__ combDst, int nmsg,
    const float* __restrict__ coefp, const float* __restrict__ deg, const float* __restrict__ bvec,
    int gmsg,
    const ushort_t* __restrict__ hd, const ushort_t* __restrict__ hs,
    const ushort_t* __restrict__ WtQ, const ushort_t* __restrict__ WtK, const ushort_t* __restrict__ WtV,
    ushort_t* __restrict__ Qb, ushort_t* __restrict__ Kb, ushort_t* __restrict__ Vb,
    int ndd, int nds) {
  __shared__ char sm[16384 + 65536];
  char* As = sm;
  char* Bs = sm + 16384;
  int tid = threadIdx.x;
  int lane = tid & 63, wv = tid >> 6;
  int i16 = lane & 15, seg = lane >> 4;
  int bb = blockIdx.x;

  if (bb < gmsg) {
    int base = bb * 64;
    stage_B<128>(Bs, tid, WtM, nullptr);
    stage_A_bf16(As, tid, Sb, base, nmsg);
    __syncthreads();
    f32x4 acc[4][2] = {};
    mfma_core<2>(As, Bs, lane, wv * 32, acc);
    float coef = *coefp;
#pragma unroll
    for (int m = 0; m < 4; m++)
#pragma unroll
      for (int i = 0; i < 4; i++) {
        int grow = base + m * 16 + seg * 4 + i;
        if (grow >= nmsg) continue;
        float dg = deg[grow];
#pragma unroll
        for (int nn = 0; nn < 2; nn++) {
          int col = wv * 32 + nn * 16 + i16;
          ushort_t* cp = &combDst[(size_t)grow * 128 + col];
          float mv = coef * (acc[m][nn][i] + dg * bvec[col]);
          if (MODE == 1) mv += b2f(*cp);
          *cp = f2b(mv);
        }
      }
    return;
  }
  bb -= gmsg;
  int nqb = (ndd + 63) >> 6;
  if (bb < nqb) {
    int base = bb * 64;
    stage_B<128>(Bs, tid, WtQ, nullptr);
    stage_A_bf16(As, tid, hd, base, ndd);
    __syncthreads();
    f32x4 acc[4][2] = {};
    mfma_core<2>(As, Bs, lane, wv * 32, acc);
#pragma unroll
    for (int m = 0; m < 4; m++)
#pragma unroll
      for (int i = 0; i < 4; i++) {
        int grow = base + m * 16 + seg * 4 + i;
        if (grow >= ndd) continue;
#pragma unroll
        for (int nn = 0; nn < 2; nn++) {
          int col = wv * 32 + nn * 16 + i16;
          Qb[(size_t)grow * 128 + col] = f2b(acc[m][nn][i]);
        }
      }
  } else {
    int base = (bb - nqb) * 64;
    stage_B<256>(Bs, tid, WtK, WtV);
    stage_A_bf16(As, tid, hs, base, nds);
    __syncthreads();
    f32x4 acc[4][4] = {};
    mfma_core<4>(As, Bs, lane, wv * 64, acc);
#pragma unroll
    for (int m = 0; m < 4; m++)
#pragma unroll
      for (int i = 0; i < 4; i++) {
        int grow = base + m * 16 + seg * 4 + i;
        if (grow >= nds) continue;
#pragma unroll
        for (int nn = 0; nn < 4; nn++) {
          int col = wv * 64 + nn * 16 + i16;
          ushort_t val = f2b(acc[m][nn][i]);
          if (col < 128) Kb[(size_t)grow * 128 + col] = val;
          else           Vb[(size_t)grow * 128 + col - 128] = val;
        }
      }
  }
}

// ---------------- CSR attention: one wave per dst node, 8 nodes/block, empty-node early exit
__global__ __launch_bounds__(512) void attn_agg(
    const ushort_t* __restrict__ Qb, const ushort_t* __restrict__ Kb, const ushort_t* __restrict__ Vb,
    const int* __restrict__ offs, const int* __restrict__ src_csr, const float* __restrict__ ew_csr,
    const float* __restrict__ ews, ushort_t* __restrict__ Sb, float* __restrict__ degb, int ndd) {
  int node = blockIdx.x * 8 + (threadIdx.x >> 6);
  if (node >= ndd) return;
  int lane = threadIdx.x & 63;
  int beg = offs[node], end = offs[node + 1];
  if (end == beg) {
    Sb[(size_t)node * 128 + lane] = 0;
    Sb[(size_t)node * 128 + 64 + lane] = 0;
    if (lane == 0) degb[node] = 0.f;
    return;
  }
  float escale = ews[0] * 0.17677669529663687f;
  float q0 = b2f(Qb[(size_t)node * 128 + lane]);
  float q1 = b2f(Qb[(size_t)node * 128 + 64 + lane]);
  float m0 = -3.0e38f, m1 = -3.0e38f, z0 = 0.f, z1 = 0.f, a0 = 0.f, a1 = 0.f;
  for (int p = beg; p < end; p++) {
    int s = src_csr[p];
    float wgt = ew_csr[p] * escale;
    float k0 = b2f(Kb[(size_t)s * 128 + lane]);
    float k1 = b2f(Kb[(size_t)s * 128 + 64 + lane]);
    float p0 = q0 * k0, p1 = q1 * k1;
#pragma unroll
    for (int mm = 16; mm; mm >>= 1) {
      p0 += __shfl_xor(p0, mm);
      p1 += __shfl_xor(p1, mm);
    }
    float s0 = p0 * wgt, s1 = p1 * wgt;
    float nm0 = fmaxf(m0, s0), nm1 = fmaxf(m1, s1);
    float r0 = expf(m0 - nm0), r1 = expf(m1 - nm1);
    float e0 = expf(s0 - nm0), e1 = expf(s1 - nm1);
    float v0 = b2f(Vb[(size_t)s * 128 + lane]);
    float v1 = b2f(Vb[(size_t)s * 128 + 64 + lane]);
    z0 = z0 * r0 + e0; a0 = a0 * r0 + e0 * v0; m0 = nm0;
    z1 = z1 * r1 + e1; a1 = a1 * r1 + e1 * v1; m1 = nm1;
  }
  Sb[(size_t)node * 128 + lane]      = f2b(a0 / (z0 + 1e-10f));
  Sb[(size_t)node * 128 + 64 + lane] = f2b(a1 / (z1 + 1e-10f));
  if (lane == 0) degb[node] = (float)(end - beg);
}

// ---------------- batched Wo GEMM + residual + in-register LN + elu (+ AIAgent elu tail)
// wave wv owns rows [wv*16, wv*16+16), ALL 128 cols (NF=8) -> LN fully intra-wave
#define WO_C1 938
#define WO_C2 1251
#define WO_C3 1876
#define WO_C4 2501
#define WO_TOTAL 2814
__global__ __launch_bounds__(256) void wo_ln_all(
    ushort_t* __restrict__ h, const ushort_t* __restrict__ comb, const ushort_t* __restrict__ Wt,
    const float* __restrict__ bo, const float* __restrict__ lng, const float* __restrict__ lnb, int l) {
  int bb = blockIdx.x;
  int tid = threadIdx.x;
  if (bb >= WO_C4) {
    int idx16 = (bb - WO_C4) * 256 + tid;
    if (idx16 >= 80000) return;
    ushort_t* p = h + (size_t)160000 * 128 + (size_t)idx16 * 16;
    uint4 v0 = *(uint4*)p, v1 = *(uint4*)(p + 8);
    unsigned* u0 = (unsigned*)&v0;
    unsigned* u1 = (unsigned*)&v1;
#pragma unroll
    for (int i = 0; i < 4; i++) {
      float2 a = b2f2(u0[i]); u0[i] = pk2(eluf(a.x), eluf(a.y));
      float2 b = b2f2(u1[i]); u1[i] = pk2(eluf(b.x), eluf(b.y));
    }
    *(uint4*)p = v0; *(uint4*)(p + 8) = v1;
    return;
  }
  int ti, lb;
  if (bb < WO_C1)      { ti = 0; lb = bb; }
  else if (bb < WO_C2) { ti = 1; lb = bb - WO_C1; }
  else if (bb < WO_C3) { ti = 2; lb = bb - WO_C2; }
  else                 { ti = 3; lb = bb - WO_C3; }
  const int ROFF_[4] = {0, 60000, 80000, 120000};
  const int NCNT4_[4] = {60000, 20000, 40000, 40000};
  int n = NCNT4_[ti];
  int base = lb * 64;
  int li = l * 5 + ti;
  const ushort_t* A = comb + (size_t)ROFF_[ti] * 128;
  ushort_t* C1 = h + (size_t)ROFF_[ti] * 128;
  const ushort_t* Bt = Wt + (size_t)(84 + li) * 16384;
  const float* bvec = bo + (size_t)li * 128;
  const float* g = lng + (size_t)li * 128;
  const float* b = lnb + (size_t)li * 128;

  __shared__ char sm[16384 + 32768];
  char* As = sm;
  char* Bs = sm + 16384;
  stage_B<128>(Bs, tid, Bt, nullptr);
  stage_A_bf16(As, tid, A, base, n);
  __syncthreads();
  int lane = tid & 63, wv = tid >> 6;
  int i16 = lane & 15, seg = lane >> 4;

  // MFMA: rows wv*16+seg*4+i, cols nn*16+i16
  f32x4 acc[8] = {};
#pragma unroll
  for (int s = 0; s < 4; s++) {
    int arow = wv * 16 + i16;
    bf16x8 a = *(const bf16x8*)(As + ((arow * 256 + s * 64 + seg * 16) ^ ((arow & 7) << 4)));
#pragma unroll
    for (int nn = 0; nn < 8; nn++) {
      int nr = nn * 16 + i16;
      bf16x8 bfr = *(const bf16x8*)(Bs + ((nr * 256 + s * 64 + seg * 16) ^ ((nr & 7) << 4)));
      acc[nn] = __builtin_amdgcn_mfma_f32_16x16x32_bf16(a, bfr, acc[nn], 0, 0, 0);
    }
  }

  float gv[8], bv[8], bov[8];
#pragma unroll
  for (int nn = 0; nn < 8; nn++) {
    int col = nn * 16 + i16;
    gv[nn] = g[col]; bv[nn] = b[col]; bov[nn] = bvec[col];
  }
#pragma unroll
  for (int i = 0; i < 4; i++) {
    int grow = base + wv * 16 + seg * 4 + i;
    if (grow >= n) continue;   // uniform across the 16-lane i16 group (row indep of i16)
    float y[8];
    float s1 = 0.f;
#pragma unroll
    for (int nn = 0; nn < 8; nn++) {
      int col = nn * 16 + i16;
      float yv = acc[nn][i] + b2f(C1[(size_t)grow * 128 + col]) + bov[nn];
      y[nn] = yv; s1 += yv;
    }
#pragma unroll
    for (int mm = 8; mm; mm >>= 1) s1 += __shfl_xor(s1, mm);
    float mu = s1 * (1.f / 128.f);
    float s2 = 0.f;
#pragma unroll
    for (int nn = 0; nn < 8; nn++) { float d = y[nn] - mu; s2 += d * d; }
#pragma unroll
    for (int mm = 8; mm; mm >>= 1) s2 += __shfl_xor(s2, mm);
    float rs = rsqrtf(s2 * (1.f / 128.f) + 1e-5f);
#pragma unroll
    for (int nn = 0; nn < 8; nn++) {
      int col = nn * 16 + i16;
      C1[(size_t)grow * 128 + col] = f2b(eluf((y[nn] - mu) * rs * gv[nn] + bv[nn]));
    }
  }
}

// ---------------- merged heads: blocks [0,G_PCAT) Pcat GEMM; [G_PCAT, 2*G_PCAT) risk head
__global__ __launch_bounds__(256) void pcat_risk(
    const ushort_t* __restrict__ Hh, const ushort_t* __restrict__ BtP1, const ushort_t* __restrict__ BtP2,
    ushort_t* __restrict__ Pcat, const ushort_t* __restrict__ Wt101,
    const float* __restrict__ br1, const float* __restrict__ Wr2, const float* __restrict__ br2,
    float* __restrict__ out) {
  __shared__ char sm[16384 + 65536];
  char* As = sm;
  char* Bs = sm + 16384;
  int tid = threadIdx.x;
  int lane = tid & 63, wv = tid >> 6;
  int i16 = lane & 15, seg = lane >> 4;
  int bb = blockIdx.x;
  if (bb < G_PCAT) {
    int base = bb * 64;
    stage_B<256>(Bs, tid, BtP1, BtP2);
    stage_A_bf16(As, tid, Hh, base, TOTROWS);
    __syncthreads();
    f32x4 acc[4][4] = {};
    mfma_core<4>(As, Bs, lane, wv * 64, acc);
#pragma unroll
    for (int m = 0; m < 4; m++)
#pragma unroll
      for (int i = 0; i < 4; i++) {
        int grow = base + m * 16 + seg * 4 + i;
        if (grow >= TOTROWS) continue;
#pragma unroll
        for (int nn = 0; nn < 4; nn++) {
          int col = wv * 64 + nn * 16 + i16;
          Pcat[(size_t)grow * 256 + col] = f2b(acc[m][nn][i]);
        }
      }
  } else {
    int base = (bb - G_PCAT) * 64;
    float* Hs = (float*)(sm + 32768);
#pragma unroll
    for (int i = 0; i < 4; i++) {
      int u = tid + i * 256;
      int nrow = u >> 4;
      uint4 w = *(const uint4*)(Wt101 + (size_t)u * 8);
      *(uint4*)(Bs + ((u * 16) ^ ((nrow & 7) << 4))) = w;
    }
    stage_A_bf16(As, tid, Hh, base, TOTROWS);
    __syncthreads();
    f32x4 acc[4][1] = {};
    mfma_core<1>(As, Bs, lane, wv * 16, acc);
#pragma unroll
    for (int m = 0; m < 4; m++)
#pragma unroll
      for (int i = 0; i < 4; i++) {
        int rl = m * 16 + seg * 4 + i;
        int col = wv * 16 + i16;
        Hs[rl * 68 + col] = eluf(acc[m][0][i] + br1[col]);
      }
    __syncthreads();
    float wr2r = Wr2[lane];
    for (int rr = 0; rr < 16; rr++) {
      int rl = wv * 16 + rr;
      int grow = base + rl;
      float v = Hs[rl * 68 + lane] * wr2r;
#pragma unroll
      for (int mm = 32; mm; mm >>= 1) v += __shfl_xor(v, mm);
      if (lane == 0 && grow < TOTROWS) out[grow] = sigf(v + br2[0]);
    }
  }
}

// ---------------- batched edge heads
__global__ __launch_bounds__(256) void edge_combine_all(
    const ushort_t* __restrict__ Pcat, const int* __restrict__ ei,
    const float* __restrict__ be1, const float* __restrict__ We2,
    const float* __restrict__ be2, float* __restrict__ out) {
  const int RSI_[7] = {0, 1, 0, 0, 2, 4, 0};
  const int RDI_[7] = {1, 1, 2, 3, 2, 3, 0};
  const int ROFF_[5] = {0, 60000, 80000, 120000, 160000};
  int bb = blockIdx.x;
  int r = bb / 10000;
  int lane = threadIdx.x & 63;
  int e = (bb % 10000) * 4 + (threadIdx.x >> 6);
  const int* src = ei + (size_t)r * 2 * EE;
  const int* dst = src + EE;
  int s = src[e], d = dst[e];
  const ushort_t* p1 = Pcat + ((size_t)(ROFF_[RSI_[r]] + s)) * 256;
  const ushort_t* p2 = Pcat + ((size_t)(ROFF_[RDI_[r]] + d)) * 256 + 128;
  float h0 = eluf(b2f(p1[lane])      + b2f(p2[lane])      + be1[lane]);
  float h1 = eluf(b2f(p1[64 + lane]) + b2f(p2[64 + lane]) + be1[64 + lane]);
  float v = h0 * We2[lane] + h1 * We2[64 + lane];
#pragma unroll
  for (int mm = 32; mm; mm >>= 1) v += __shfl_xor(v, mm);
  if (lane == 0) out[TOTROWS + (size_t)r * EE + e] = sigf(v + be2[0]);
}

extern "C" void kernel_launch(void* const* d_in, const int* in_sizes, int n_in,
                              void* d_out, int out_size, void* d_ws, size_t ws_size,
                              hipStream_t stream) {
  (void)in_sizes; (void)n_in; (void)out_size;
  static const int NCNT_[5] = {60000, 20000, 40000, 40000, 10000};
  static const int RSI[7] = {0, 1, 0, 0, 2, 4, 0};
  static const int RDI[7] = {1, 1, 2, 3, 2, 3, 0};
  static const int RFIRST[7] = {1, 0, 1, 1, 0, 0, 1};
  static const int ROFF[5] = {0, 60000, 80000, 120000, 160000};

  const float* x[5];    for (int i = 0; i < 5; i++) x[i] = (const float*)d_in[i];
  const int*   ei     = (const int*)d_in[5];
  const float* ew     = (const float*)d_in[6];
  const float* theta  = (const float*)d_in[7];
  const float* Win[5]; for (int i = 0; i < 5; i++) Win[i] = (const float*)d_in[8 + i];
  const float* b_in   = (const float*)d_in[13];
  const float* Wq     = (const float*)d_in[14];
  const float* Wk     = (const float*)d_in[15];
  const float* Wv     = (const float*)d_in[16];
  const float* Wmsg   = (const float*)d_in[17];
  const float* bmsg   = (const float*)d_in[18];
  const float* relimp = (const float*)d_in[19];
  const float* Wo     = (const float*)d_in[20];
  const float* bo     = (const float*)d_in[21];
  const float* lng    = (const float*)d_in[22];
  const float* lnb    = (const float*)d_in[23];
  const float* Wr1    = (const float*)d_in[24];
  const float* br1    = (const float*)d_in[25];
  const float* Wr2    = (const float*)d_in[26];
  const float* br2    = (const float*)d_in[27];
  const float* We1    = (const float*)d_in[28];
  const float* be1    = (const float*)d_in[29];
  const float* We2    = (const float*)d_in[30];
  const float* be2    = (const float*)d_in[31];
  float* out = (float*)d_out;

  // ---- workspace ----
  char* ws = (char*)d_ws;
  size_t off = 0;
  auto alloc = [&](size_t bytes) -> void* {
    void* p = (void*)(ws + off);
    off = (off + bytes + 255) & ~(size_t)255;
    return p;
  };
  ushort_t* h    = (ushort_t*)alloc((size_t)TOTROWS * 128 * 2);
  ushort_t* comb = (ushort_t*)alloc((size_t)TOTROWS * 128 * 2);
  ushort_t* Qb   = (ushort_t*)alloc((size_t)60000 * 128 * 2);
  ushort_t* Kb   = (ushort_t*)alloc((size_t)60000 * 128 * 2);
  ushort_t* Vb   = (ushort_t*)alloc((size_t)60000 * 128 * 2);
  ushort_t* Sb   = (ushort_t*)alloc((size_t)60000 * 128 * 2);
  float* degb = (float*)alloc((size_t)60000 * 4);
  ushort_t* Wt = (ushort_t*)alloc((size_t)102 * 16384 * 2);
  int* counts  = (int*)alloc((size_t)7 * NDOFF * 4);
  int* cursor  = (int*)alloc((size_t)7 * NDOFF * 4);
  int* offsb   = (int*)alloc((size_t)7 * NDOFF * 4);
  int* src_csr = (int*)alloc((size_t)7 * EE * 4);
  float* ew_csr = (float*)alloc((size_t)7 * EE * 4);
  int* chunkS  = (int*)alloc((size_t)7 * NCHK * 4);
  int* chunkO  = (int*)alloc((size_t)7 * NCHK * 4);
  float* scal = (float*)alloc(256);
  if (off > ws_size) return;
  ushort_t* Pcat = comb;       // reuse after layers

  prep_scalars<<<1, 64, 0, stream>>>(theta, relimp, scal);
  transpose_weights<<<101, 256, 0, stream>>>(Wq, Wk, Wv, Wmsg, Wo, We1, Wt);
  transpose_wr1<<<32, 256, 0, stream>>>(Wr1, Wt + (size_t)101 * 16384);

  in_proj_all<<<2658, 256, 0, stream>>>(
      x[0], x[1], x[2], x[3], x[4], Win[0], Win[1], Win[2], Win[3], Win[4], b_in, h);

  csr_clear<<<CDIV(7 * NDOFF, 256), 256, 0, stream>>>(counts);
  csr_hist<<<CDIV(7 * EE, 256), 256, 0, stream>>>(ei, counts);
  csr_chunk<<<7 * NCHK, 256, 0, stream>>>(counts, chunkS);
  csr_chunkscan<<<1, 64, 0, stream>>>(chunkS, chunkO);
  csr_scan_final<<<7 * NCHK, 1024, 0, stream>>>(counts, chunkO, offsb, cursor);
  csr_scatter<<<CDIV(7 * EE, 256), 256, 0, stream>>>(ei, ew, cursor, src_csr, ew_csr);

  for (int l = 0; l < 3; l++) {
    for (int r = 0; r < 7; r++) {
      int si = RSI[r], di = RDI[r];
      int nds = NCNT_[si], ndd = NCNT_[di];
      ushort_t* hs = h + (size_t)ROFF[si] * 128;
      ushort_t* hd = h + (size_t)ROFF[di] * 128;
      int lr = l * 7 + r;
      const ushort_t* WtQ = Wt + (size_t)lr * 16384;
      const ushort_t* WtK = Wt + (size_t)(21 + lr) * 16384;
      const ushort_t* WtV = Wt + (size_t)(42 + lr) * 16384;
      int gq = CDIV(ndd, 64), gkv = CDIV(nds, 64);

      if (r == 0) {
        msg_qkv<4><<<gq + gkv, 256, 0, stream>>>(
            nullptr, nullptr, nullptr, 0, scal, scal, scal, 0,
            hd, hs, WtQ, WtK, WtV, Qb, Kb, Vb, ndd, nds);
      } else {
        int pr = r - 1, plr = l * 7 + pr;
        int nmsg = NCNT_[RDI[pr]];
        int gm = CDIV(nmsg, 64);
        ushort_t* pdst = comb + (size_t)ROFF[RDI[pr]] * 128;
        const ushort_t* WtMp = Wt + (size_t)(63 + plr) * 16384;
        if (RFIRST[pr])
          msg_qkv<4><<<gm + gq + gkv, 256, 0, stream>>>(
              Sb, WtMp, pdst, nmsg, scal + 8 + plr, degb, bmsg + (size_t)plr * 128, gm,
              hd, hs, WtQ, WtK, WtV, Qb, Kb, Vb, ndd, nds);
        else
          msg_qkv<1><<<gm + gq + gkv, 256, 0, stream>>>(
              Sb, WtMp, pdst, nmsg, scal + 8 + plr, degb, bmsg + (size_t)plr * 128, gm,
              hd, hs, WtQ, WtK, WtV, Qb, Kb, Vb, ndd, nds);
      }
      attn_agg<<<CDIV(ndd, 8), 512, 0, stream>>>(
          Qb, Kb, Vb, offsb + (size_t)r * NDOFF, src_csr + (size_t)r * EE,
          ew_csr + (size_t)r * EE, scal + r, Sb, degb, ndd);
    }
    // trailing msg for r=6 (RFIRST[6]=1 -> MODE 4)
    {
      int plr = l * 7 + 6;
      int nmsg = NCNT_[RDI[6]];
      int gm = CDIV(nmsg, 64);
      msg_qkv<4><<<gm, 256, 0, stream>>>(
          Sb, Wt + (size_t)(63 + plr) * 16384, comb + (size_t)ROFF[RDI[6]] * 128, nmsg,
          scal + 8 + plr, degb, bmsg + (size_t)plr * 128, gm,
          nullptr, nullptr, nullptr, nullptr, nullptr, nullptr, nullptr, nullptr, 0, 0);
    }
    wo_ln_all<<<WO_TOTAL, 256, 0, stream>>>(h, comb, Wt, bo, lng, lnb, l);
  }

  // ---- heads ----
  pcat_risk<<<2 * G_PCAT, 256, 0, stream>>>(
      h, Wt + (size_t)99 * 16384, Wt + (size_t)100 * 16384, Pcat,
      Wt + (size_t)101 * 16384, br1, Wr2, br2, out);

  edge_combine_all<<<7 * CDIV(EE, 4), 256, 0, stream>>>(Pcat, ei, be1, We2, be2, out);
}

// Round 12
// 1324.156 us; speedup vs baseline: 1.5108x; 1.2160x over previous
//
#include <hip/hip_runtime.h>

#define CDIV(a,b) (((a)+(b)-1)/(b))
#define EE 40000
#define TOTROWS 170000
#define NDOFF 60001
#define NCHK 59
#define G_PCAT 2657

typedef unsigned short ushort_t;
typedef short bf16x8 __attribute__((ext_vector_type(8)));
typedef float f32x4 __attribute__((ext_vector_type(4)));

__device__ __forceinline__ float eluf(float x) { return x > 0.f ? x : expm1f(x); }
__device__ __forceinline__ float sigf(float x) { return 1.f / (1.f + expf(-x)); }
__device__ __forceinline__ float b2f(ushort_t u) { return __uint_as_float(((unsigned)u) << 16); }
__device__ __forceinline__ ushort_t f2b(float f) {
  unsigned x = __float_as_uint(f);
  x += 0x7FFFu + ((x >> 16) & 1u);
  return (ushort_t)(x >> 16);
}
__device__ __forceinline__ unsigned pk2(float lo, float hi) {
  return (unsigned)f2b(lo) | ((unsigned)f2b(hi) << 16);
}
__device__ __forceinline__ float2 b2f2(unsigned u) {
  return make_float2(__uint_as_float(u << 16), __uint_as_float(u & 0xFFFF0000u));
}

__constant__ const int NDD_C[7] = {20000, 20000, 40000, 40000, 40000, 40000, 60000};

// ======== shared MFMA helpers (A: [64][128] bf16 swizzled; B: [128][128] bf16 swizzled) ========
__device__ __forceinline__ void stage_B128(char* Bs, int tid, const ushort_t* Bt) {
#pragma unroll
  for (int i = 0; i < 8; i++) {
    int u = tid + i * 256;
    int nrow = u >> 4;
    uint4 w = *(const uint4*)(Bt + (size_t)u * 8);
    *(uint4*)(Bs + ((u * 16) ^ ((nrow & 7) << 4))) = w;
  }
}

__device__ __forceinline__ void stage_A_bf16(char* As, int tid, const ushort_t* Ab, int base, int n) {
#pragma unroll
  for (int i = 0; i < 4; i++) {
    int u = tid + i * 256;
    int row = u >> 4;
    int grow = base + row;
    uint4 v = make_uint4(0, 0, 0, 0);
    if (grow < n) v = *(const uint4*)&Ab[(size_t)grow * 128 + (u & 15) * 8];
    *(uint4*)(As + ((u * 16) ^ ((row & 7) << 4))) = v;
  }
}

template<int NF>
__device__ __forceinline__ void mfma_core(const char* As, const char* Bs, int lane, int wcol,
                                          f32x4 (&acc)[4][NF]) {
  int i16 = lane & 15, seg = lane >> 4;
#pragma unroll
  for (int s = 0; s < 4; s++) {
    bf16x8 a[4], b[NF];
#pragma unroll
    for (int m = 0; m < 4; m++) {
      int row = m * 16 + i16;
      a[m] = *(const bf16x8*)(As + ((row * 256 + s * 64 + seg * 16) ^ ((row & 7) << 4)));
    }
#pragma unroll
    for (int nn = 0; nn < NF; nn++) {
      int nr = wcol + nn * 16 + i16;
      b[nn] = *(const bf16x8*)(Bs + ((nr * 256 + s * 64 + seg * 16) ^ ((nr & 7) << 4)));
    }
#pragma unroll
    for (int m = 0; m < 4; m++)
#pragma unroll
      for (int nn = 0; nn < NF; nn++)
        acc[m][nn] = __builtin_amdgcn_mfma_f32_16x16x32_bf16(a[m], b[nn], acc[m][nn], 0, 0, 0);
  }
}

// ---------------- scalar prep
__global__ void prep_scalars(const float* __restrict__ theta, const float* __restrict__ rel_imp,
                             float* __restrict__ scal) {
  int t = threadIdx.x;
  if (t < 7) scal[t] = 1.f - sigf(theta[t]);
  if (t < 21) {
    const int partner[7] = {1, 0, 4, 5, 2, 3, -1};
    int l = t / 7, r = t % 7;
    float rw = sigf(rel_imp[t]);
    float w;
    if (partner[r] < 0) w = 1.f;
    else {
      float rwp = sigf(rel_imp[l * 7 + partner[r]]);
      float e0 = expf(rw), e1 = expf(rwp);
      w = e0 / (e0 + e1);
    }
    scal[8 + t] = w * rw;
  }
}

// ---------------- weight transpose + bf16 cast
__global__ __launch_bounds__(256) void transpose_weights(
    const float* __restrict__ Wq, const float* __restrict__ Wk, const float* __restrict__ Wv,
    const float* __restrict__ Wmsg, const float* __restrict__ Wo, const float* __restrict__ We1,
    ushort_t* __restrict__ Wt) {
  int mat = blockIdx.x;
  const float* src;
  if (mat < 21)      src = Wq   + (size_t)mat * 16384;
  else if (mat < 42) src = Wk   + (size_t)(mat - 21) * 16384;
  else if (mat < 63) src = Wv   + (size_t)(mat - 42) * 16384;
  else if (mat < 84) src = Wmsg + (size_t)(mat - 63) * 16384;
  else if (mat < 99) src = Wo   + (size_t)(mat - 84) * 16384;
  else               src = We1  + (size_t)(mat - 99) * 16384;
  __shared__ ushort_t lds[16384];
  int t = threadIdx.x;
  for (int i = 0; i < 64; i++) {
    int u = t + i * 256;            // u = k*128 + n
    int k = u >> 7;
    int byte = (u * 2) ^ ((k & 15) << 2);
    *(ushort_t*)((char*)lds + byte) = f2b(src[u]);
  }
  __syncthreads();
  ushort_t* dst = Wt + (size_t)mat * 16384;
  for (int i = 0; i < 64; i++) {
    int u = t + i * 256;            // u = n*128 + k
    int n = u >> 7, k = u & 127;
    int byte = ((k * 128 + n) * 2) ^ ((k & 15) << 2);
    dst[u] = *(ushort_t*)((char*)lds + byte);
  }
}

__global__ void transpose_wr1(const float* __restrict__ Wr1, ushort_t* __restrict__ Wt101) {
  int u = blockIdx.x * 256 + threadIdx.x;   // 8192
  int n = u >> 7, k = u & 127;
  Wt101[u] = f2b(Wr1[k * 64 + n]);
}

// ---------------- input projection: LDS-staged, templated-F, 64 rows/block
template<int F>
__device__ __forceinline__ void inproj_compute(const float* xs, const float* Ws, const float* b2,
                                               ushort_t* hptr, int base, int n, int tid) {
  int cp = tid & 63, rg = tid >> 6;
  float wc0[F], wc1[F];
#pragma unroll
  for (int f = 0; f < F; f++) {
    wc0[f] = Ws[f * 128 + cp * 2];
    wc1[f] = Ws[f * 128 + cp * 2 + 1];
  }
  float bb0 = b2[cp * 2], bb1 = b2[cp * 2 + 1];
  for (int i = 0; i < 16; i++) {
    int row = rg * 16 + i, grow = base + row;
    if (grow >= n) break;
    float a0 = bb0, a1 = bb1;
#pragma unroll
    for (int f = 0; f < F; f++) {
      float xv = xs[row * F + f];
      a0 = fmaf(xv, wc0[f], a0);
      a1 = fmaf(xv, wc1[f], a1);
    }
    *(unsigned*)&hptr[(size_t)grow * 128 + cp * 2] = pk2(eluf(a0), eluf(a1));
  }
}

__global__ __launch_bounds__(256) void in_proj_all(
    const float* __restrict__ x0, const float* __restrict__ x1, const float* __restrict__ x2,
    const float* __restrict__ x3, const float* __restrict__ x4,
    const float* __restrict__ W0, const float* __restrict__ W1, const float* __restrict__ W2,
    const float* __restrict__ W3, const float* __restrict__ W4,
    const float* __restrict__ b_in, ushort_t* __restrict__ h) {
  __shared__ float xs[64 * 22];
  __shared__ float Ws[22 * 128];
  int bb = blockIdx.x, tid = threadIdx.x;
  int ti, lb;
  if (bb < 938)       { ti = 0; lb = bb; }
  else if (bb < 1251) { ti = 1; lb = bb - 938; }
  else if (bb < 1876) { ti = 2; lb = bb - 1251; }
  else if (bb < 2501) { ti = 3; lb = bb - 1876; }
  else                { ti = 4; lb = bb - 2501; }
  const int ROFF_[5] = {0, 60000, 80000, 120000, 160000};
  const int NCNT_[5] = {60000, 20000, 40000, 40000, 10000};
  const int FEAT_[5] = {22, 6, 14, 5, 9};
  const float* xp = (ti == 0) ? x0 : (ti == 1) ? x1 : (ti == 2) ? x2 : (ti == 3) ? x3 : x4;
  const float* Wp = (ti == 0) ? W0 : (ti == 1) ? W1 : (ti == 2) ? W2 : (ti == 3) ? W3 : W4;
  int F = FEAT_[ti], n = NCNT_[ti], base = lb * 64;
  for (int u = tid; u < F * 128; u += 256) Ws[u] = Wp[u];
  for (int u = tid; u < 64 * F; u += 256) {
    int row = u / F, f = u - row * F, grow = base + row;
    xs[u] = (grow < n) ? xp[(size_t)grow * F + f] : 0.f;
  }
  __syncthreads();
  ushort_t* hptr = h + (size_t)ROFF_[ti] * 128;
  const float* b2 = b_in + ti * 128;
  switch (ti) {
    case 0: inproj_compute<22>(xs, Ws, b2, hptr, base, n, tid); break;
    case 1: inproj_compute<6>(xs, Ws, b2, hptr, base, n, tid); break;
    case 2: inproj_compute<14>(xs, Ws, b2, hptr, base, n, tid); break;
    case 3: inproj_compute<5>(xs, Ws, b2, hptr, base, n, tid); break;
    default: inproj_compute<9>(xs, Ws, b2, hptr, base, n, tid); break;
  }
}

// ================= CSR build =================
__global__ void csr_clear(int* __restrict__ counts) {
  int idx = blockIdx.x * 256 + threadIdx.x;
  if (idx < 7 * NDOFF) counts[idx] = 0;
}

__global__ void csr_hist(const int* __restrict__ ei, int* __restrict__ counts) {
  int idx = blockIdx.x * 256 + threadIdx.x;
  if (idx >= 7 * EE) return;
  int r = idx / EE, e = idx - r * EE;
  int d = ei[(size_t)r * 2 * EE + EE + e];
  atomicAdd(&counts[r * NDOFF + d], 1);
}

__global__ __launch_bounds__(256) void csr_chunk(const int* __restrict__ counts, int* __restrict__ chunkSums) {
  int bb = blockIdx.x;
  int r = bb / NCHK, c = bb - r * NCHK;
  int ndd = NDD_C[r];
  int t = threadIdx.x;
  int v = 0;
#pragma unroll
  for (int j = 0; j < 4; j++) {
    int idx = c * 1024 + t + j * 256;
    if (idx < ndd) v += counts[r * NDOFF + idx];
  }
#pragma unroll
  for (int mm = 32; mm; mm >>= 1) v += __shfl_xor(v, mm);
  __shared__ int ws_[4];
  if ((t & 63) == 0) ws_[t >> 6] = v;
  __syncthreads();
  if (t == 0) chunkSums[bb] = ws_[0] + ws_[1] + ws_[2] + ws_[3];
}

__global__ void csr_chunkscan(const int* __restrict__ chunkSums, int* __restrict__ chunkOffs) {
  int r = threadIdx.x;
  if (r >= 7) return;
  int run = 0;
  for (int c = 0; c < NCHK; c++) {
    chunkOffs[r * NCHK + c] = run;
    run += chunkSums[r * NCHK + c];
  }
}

__global__ __launch_bounds__(1024) void csr_scan_final(
    const int* __restrict__ counts, const int* __restrict__ chunkOffs,
    int* __restrict__ offs, int* __restrict__ cursor) {
  int bb = blockIdx.x;
  int r = bb / NCHK, c = bb - r * NCHK;
  int ndd = NDD_C[r];
  int t = threadIdx.x;
  int idx = c * 1024 + t;
  int v = (idx < ndd) ? counts[r * NDOFF + idx] : 0;
  __shared__ int sc[1024];
  sc[t] = v;
  __syncthreads();
  for (int s = 1; s < 1024; s <<= 1) {
    int add = (t >= s) ? sc[t - s] : 0;
    __syncthreads();
    sc[t] += add;
    __syncthreads();
  }
  if (idx < ndd) {
    int excl = chunkOffs[r * NCHK + c] + sc[t] - v;
    offs[r * NDOFF + idx] = excl;
    cursor[r * NDOFF + idx] = excl;
  }
  if (t == 0 && c == 0) offs[r * NDOFF + ndd] = EE;
}

__global__ void csr_scatter(const int* __restrict__ ei, const float* __restrict__ ew,
                            int* __restrict__ cursor, int* __restrict__ src_csr,
                            float* __restrict__ ew_csr) {
  int idx = blockIdx.x * 256 + threadIdx.x;
  if (idx >= 7 * EE) return;
  int r = idx / EE, e = idx - r * EE;
  int d = ei[(size_t)r * 2 * EE + EE + e];
  int s = ei[(size_t)r * 2 * EE + e];
  int slot = atomicAdd(&cursor[r * NDOFF + d], 1);
  src_csr[r * EE + slot] = s;
  ew_csr[r * EE + slot] = ew[(size_t)r * EE + e];
}

// ---------------- fused launch: msg-GEMM (prev relation) + QKV (current relation)
// All GEMM passes are BN=128 (LDS 48K -> 3 blocks/CU). KV = two passes over same A.
template<int MODE>
__global__ __launch_bounds__(256) void msg_qkv(
    const ushort_t* __restrict__ Sb, const ushort_t* __restrict__ WtM,
    ushort_t* __restrict__ combDst, int nmsg,
    const float* __restrict__ coefp, const float* __restrict__ deg, const float* __restrict__ bvec,
    int gmsg,
    const ushort_t* __restrict__ hd, const ushort_t* __restrict__ hs,
    const ushort_t* __restrict__ WtQ, const ushort_t* __restrict__ WtK, const ushort_t* __restrict__ WtV,
    ushort_t* __restrict__ Qb, ushort_t* __restrict__ Kb, ushort_t* __restrict__ Vb,
    int ndd, int nds) {
  __shared__ char sm[16384 + 32768];
  char* As = sm;
  char* Bs = sm + 16384;
  int tid = threadIdx.x;
  int lane = tid & 63, wv = tid >> 6;
  int i16 = lane & 15, seg = lane >> 4;
  int bb = blockIdx.x;

  if (bb < gmsg) {
    int base = bb * 64;
    stage_B128(Bs, tid, WtM);
    stage_A_bf16(As, tid, Sb, base, nmsg);
    __syncthreads();
    f32x4 acc[4][2] = {};
    mfma_core<2>(As, Bs, lane, wv * 32, acc);
    float coef = *coefp;
#pragma unroll
    for (int m = 0; m < 4; m++)
#pragma unroll
      for (int i = 0; i < 4; i++) {
        int grow = base + m * 16 + seg * 4 + i;
        if (grow >= nmsg) continue;
        float dg = deg[grow];
#pragma unroll
        for (int nn = 0; nn < 2; nn++) {
          int col = wv * 32 + nn * 16 + i16;
          ushort_t* cp = &combDst[(size_t)grow * 128 + col];
          float mv = coef * (acc[m][nn][i] + dg * bvec[col]);
          if (MODE == 1) mv += b2f(*cp);
          *cp = f2b(mv);
        }
      }
    return;
  }
  bb -= gmsg;
  int nqb = (ndd + 63) >> 6;
  if (bb < nqb) {
    int base = bb * 64;
    stage_B128(Bs, tid, WtQ);
    stage_A_bf16(As, tid, hd, base, ndd);
    __syncthreads();
    f32x4 acc[4][2] = {};
    mfma_core<2>(As, Bs, lane, wv * 32, acc);
#pragma unroll
    for (int m = 0; m < 4; m++)
#pragma unroll
      for (int i = 0; i < 4; i++) {
        int grow = base + m * 16 + seg * 4 + i;
        if (grow >= ndd) continue;
#pragma unroll
        for (int nn = 0; nn < 2; nn++) {
          int col = wv * 32 + nn * 16 + i16;
          Qb[(size_t)grow * 128 + col] = f2b(acc[m][nn][i]);
        }
      }
  } else {
    int base = (bb - nqb) * 64;
    stage_A_bf16(As, tid, hs, base, nds);
    stage_B128(Bs, tid, WtK);
    __syncthreads();
    {
      f32x4 acc[4][2] = {};
      mfma_core<2>(As, Bs, lane, wv * 32, acc);
#pragma unroll
      for (int m = 0; m < 4; m++)
#pragma unroll
        for (int i = 0; i < 4; i++) {
          int grow = base + m * 16 + seg * 4 + i;
          if (grow >= nds) continue;
#pragma unroll
          for (int nn = 0; nn < 2; nn++) {
            int col = wv * 32 + nn * 16 + i16;
            Kb[(size_t)grow * 128 + col] = f2b(acc[m][nn][i]);
          }
        }
    }
    __syncthreads();               // all Bs reads done
    stage_B128(Bs, tid, WtV);
    __syncthreads();
    {
      f32x4 acc[4][2] = {};
      mfma_core<2>(As, Bs, lane, wv * 32, acc);
#pragma unroll
      for (int m = 0; m < 4; m++)
#pragma unroll
        for (int i = 0; i < 4; i++) {
          int grow = base + m * 16 + seg * 4 + i;
          if (grow >= nds) continue;
#pragma unroll
          for (int nn = 0; nn < 2; nn++) {
            int col = wv * 32 + nn * 16 + i16;
            Vb[(size_t)grow * 128 + col] = f2b(acc[m][nn][i]);
          }
        }
    }
  }
}

// ---------------- CSR attention: one wave per dst node, 8 nodes/block, empty-node early exit
__global__ __launch_bounds__(512) void attn_agg(
    const ushort_t* __restrict__ Qb, const ushort_t* __restrict__ Kb, const ushort_t* __restrict__ Vb,
    const int* __restrict__ offs, const int* __restrict__ src_csr, const float* __restrict__ ew_csr,
    const float* __restrict__ ews, ushort_t* __restrict__ Sb, float* __restrict__ degb, int ndd) {
  int node = blockIdx.x * 8 + (threadIdx.x >> 6);
  if (node >= ndd) return;
  int lane = threadIdx.x & 63;
  int beg = offs[node], end = offs[node + 1];
  if (end == beg) {
    Sb[(size_t)node * 128 + lane] = 0;
    Sb[(size_t)node * 128 + 64 + lane] = 0;
    if (lane == 0) degb[node] = 0.f;
    return;
  }
  float escale = ews[0] * 0.17677669529663687f;
  float q0 = b2f(Qb[(size_t)node * 128 + lane]);
  float q1 = b2f(Qb[(size_t)node * 128 + 64 + lane]);
  float m0 = -3.0e38f, m1 = -3.0e38f, z0 = 0.f, z1 = 0.f, a0 = 0.f, a1 = 0.f;
  for (int p = beg; p < end; p++) {
    int s = src_csr[p];
    float wgt = ew_csr[p] * escale;
    float k0 = b2f(Kb[(size_t)s * 128 + lane]);
    float k1 = b2f(Kb[(size_t)s * 128 + 64 + lane]);
    float p0 = q0 * k0, p1 = q1 * k1;
#pragma unroll
    for (int mm = 16; mm; mm >>= 1) {
      p0 += __shfl_xor(p0, mm);
      p1 += __shfl_xor(p1, mm);
    }
    float s0 = p0 * wgt, s1 = p1 * wgt;
    float nm0 = fmaxf(m0, s0), nm1 = fmaxf(m1, s1);
    float r0 = expf(m0 - nm0), r1 = expf(m1 - nm1);
    float e0 = expf(s0 - nm0), e1 = expf(s1 - nm1);
    float v0 = b2f(Vb[(size_t)s * 128 + lane]);
    float v1 = b2f(Vb[(size_t)s * 128 + 64 + lane]);
    z0 = z0 * r0 + e0; a0 = a0 * r0 + e0 * v0; m0 = nm0;
    z1 = z1 * r1 + e1; a1 = a1 * r1 + e1 * v1; m1 = nm1;
  }
  Sb[(size_t)node * 128 + lane]      = f2b(a0 / (z0 + 1e-10f));
  Sb[(size_t)node * 128 + 64 + lane] = f2b(a1 / (z1 + 1e-10f));
  if (lane == 0) degb[node] = (float)(end - beg);
}

// ---------------- batched Wo GEMM + residual + in-register LN + elu (+ AIAgent elu tail)
#define WO_C1 938
#define WO_C2 1251
#define WO_C3 1876
#define WO_C4 2501
#define WO_TOTAL 2814
__global__ __launch_bounds__(256) void wo_ln_all(
    ushort_t* __restrict__ h, const ushort_t* __restrict__ comb, const ushort_t* __restrict__ Wt,
    const float* __restrict__ bo, const float* __restrict__ lng, const float* __restrict__ lnb, int l) {
  int bb = blockIdx.x;
  int tid = threadIdx.x;
  if (bb >= WO_C4) {
    int idx16 = (bb - WO_C4) * 256 + tid;
    if (idx16 >= 80000) return;
    ushort_t* p = h + (size_t)160000 * 128 + (size_t)idx16 * 16;
    uint4 v0 = *(uint4*)p, v1 = *(uint4*)(p + 8);
    unsigned* u0 = (unsigned*)&v0;
    unsigned* u1 = (unsigned*)&v1;
#pragma unroll
    for (int i = 0; i < 4; i++) {
      float2 a = b2f2(u0[i]); u0[i] = pk2(eluf(a.x), eluf(a.y));
      float2 b = b2f2(u1[i]); u1[i] = pk2(eluf(b.x), eluf(b.y));
    }
    *(uint4*)p = v0; *(uint4*)(p + 8) = v1;
    return;
  }
  int ti, lb;
  if (bb < WO_C1)      { ti = 0; lb = bb; }
  else if (bb < WO_C2) { ti = 1; lb = bb - WO_C1; }
  else if (bb < WO_C3) { ti = 2; lb = bb - WO_C2; }
  else                 { ti = 3; lb = bb - WO_C3; }
  const int ROFF_[4] = {0, 60000, 80000, 120000};
  const int NCNT4_[4] = {60000, 20000, 40000, 40000};
  int n = NCNT4_[ti];
  int base = lb * 64;
  int li = l * 5 + ti;
  const ushort_t* A = comb + (size_t)ROFF_[ti] * 128;
  ushort_t* C1 = h + (size_t)ROFF_[ti] * 128;
  const ushort_t* Bt = Wt + (size_t)(84 + li) * 16384;
  const float* bvec = bo + (size_t)li * 128;
  const float* g = lng + (size_t)li * 128;
  const float* b = lnb + (size_t)li * 128;

  __shared__ char sm[16384 + 32768];
  char* As = sm;
  char* Bs = sm + 16384;
  stage_B128(Bs, tid, Bt);
  stage_A_bf16(As, tid, A, base, n);
  __syncthreads();
  int lane = tid & 63, wv = tid >> 6;
  int i16 = lane & 15, seg = lane >> 4;

  // MFMA: rows wv*16+seg*4+i, cols nn*16+i16
  f32x4 acc[8] = {};
#pragma unroll
  for (int s = 0; s < 4; s++) {
    int arow = wv * 16 + i16;
    bf16x8 a = *(const bf16x8*)(As + ((arow * 256 + s * 64 + seg * 16) ^ ((arow & 7) << 4)));
#pragma unroll
    for (int nn = 0; nn < 8; nn++) {
      int nr = nn * 16 + i16;
      bf16x8 bfr = *(const bf16x8*)(Bs + ((nr * 256 + s * 64 + seg * 16) ^ ((nr & 7) << 4)));
      acc[nn] = __builtin_amdgcn_mfma_f32_16x16x32_bf16(a, bfr, acc[nn], 0, 0, 0);
    }
  }

  float gv[8], bv[8], bov[8];
#pragma unroll
  for (int nn = 0; nn < 8; nn++) {
    int col = nn * 16 + i16;
    gv[nn] = g[col]; bv[nn] = b[col]; bov[nn] = bvec[col];
  }
#pragma unroll
  for (int i = 0; i < 4; i++) {
    int grow = base + wv * 16 + seg * 4 + i;
    if (grow >= n) continue;   // uniform across the 16-lane i16 group
    float y[8];
    float s1 = 0.f;
#pragma unroll
    for (int nn = 0; nn < 8; nn++) {
      int col = nn * 16 + i16;
      float yv = acc[nn][i] + b2f(C1[(size_t)grow * 128 + col]) + bov[nn];
      y[nn] = yv; s1 += yv;
    }
#pragma unroll
    for (int mm = 8; mm; mm >>= 1) s1 += __shfl_xor(s1, mm);
    float mu = s1 * (1.f / 128.f);
    float s2 = 0.f;
#pragma unroll
    for (int nn = 0; nn < 8; nn++) { float d = y[nn] - mu; s2 += d * d; }
#pragma unroll
    for (int mm = 8; mm; mm >>= 1) s2 += __shfl_xor(s2, mm);
    float rs = rsqrtf(s2 * (1.f / 128.f) + 1e-5f);
#pragma unroll
    for (int nn = 0; nn < 8; nn++) {
      int col = nn * 16 + i16;
      C1[(size_t)grow * 128 + col] = f2b(eluf((y[nn] - mu) * rs * gv[nn] + bv[nn]));
    }
  }
}

// ---------------- merged heads: blocks [0,G_PCAT) Pcat GEMM (2x BN=128); [G_PCAT, 2*G_PCAT) risk head
__global__ __launch_bounds__(256) void pcat_risk(
    const ushort_t* __restrict__ Hh, const ushort_t* __restrict__ BtP1, const ushort_t* __restrict__ BtP2,
    ushort_t* __restrict__ Pcat, const ushort_t* __restrict__ Wt101,
    const float* __restrict__ br1, const float* __restrict__ Wr2, const float* __restrict__ br2,
    float* __restrict__ out) {
  __shared__ char sm[16384 + 32768];
  char* As = sm;
  char* Bs = sm + 16384;
  int tid = threadIdx.x;
  int lane = tid & 63, wv = tid >> 6;
  int i16 = lane & 15, seg = lane >> 4;
  int bb = blockIdx.x;
  if (bb < G_PCAT) {
    int base = bb * 64;
    stage_A_bf16(As, tid, Hh, base, TOTROWS);
    stage_B128(Bs, tid, BtP1);
    __syncthreads();
    {
      f32x4 acc[4][2] = {};
      mfma_core<2>(As, Bs, lane, wv * 32, acc);
#pragma unroll
      for (int m = 0; m < 4; m++)
#pragma unroll
        for (int i = 0; i < 4; i++) {
          int grow = base + m * 16 + seg * 4 + i;
          if (grow >= TOTROWS) continue;
#pragma unroll
          for (int nn = 0; nn < 2; nn++) {
            int col = wv * 32 + nn * 16 + i16;
            Pcat[(size_t)grow * 256 + col] = f2b(acc[m][nn][i]);
          }
        }
    }
    __syncthreads();
    stage_B128(Bs, tid, BtP2);
    __syncthreads();
    {
      f32x4 acc[4][2] = {};
      mfma_core<2>(As, Bs, lane, wv * 32, acc);
#pragma unroll
      for (int m = 0; m < 4; m++)
#pragma unroll
        for (int i = 0; i < 4; i++) {
          int grow = base + m * 16 + seg * 4 + i;
          if (grow >= TOTROWS) continue;
#pragma unroll
          for (int nn = 0; nn < 2; nn++) {
            int col = 128 + wv * 32 + nn * 16 + i16;
            Pcat[(size_t)grow * 256 + col] = f2b(acc[m][nn][i]);
          }
        }
    }
  } else {
    int base = (bb - G_PCAT) * 64;
    // stage Wr1 [64][128] into Bs (16K)
#pragma unroll
    for (int i = 0; i < 4; i++) {
      int u = tid + i * 256;
      int nrow = u >> 4;
      uint4 w = *(const uint4*)(Wt101 + (size_t)u * 8);
      *(uint4*)(Bs + ((u * 16) ^ ((nrow & 7) << 4))) = w;
    }
    stage_A_bf16(As, tid, Hh, base, TOTROWS);
    __syncthreads();
    f32x4 acc[4][1] = {};
    mfma_core<1>(As, Bs, lane, wv * 16, acc);
    __syncthreads();               // As/Bs reads complete; overlay Hs
    float* Hs = (float*)sm;        // 64*68*4 = 17408 B within 48K
#pragma unroll
    for (int m = 0; m < 4; m++)
#pragma unroll
      for (int i = 0; i < 4; i++) {
        int rl = m * 16 + seg * 4 + i;
        int col = wv * 16 + i16;
        Hs[rl * 68 + col] = eluf(acc[m][0][i] + br1[col]);
      }
    __syncthreads();
    float wr2r = Wr2[lane];
    for (int rr = 0; rr < 16; rr++) {
      int rl = wv * 16 + rr;
      int grow = base + rl;
      float v = Hs[rl * 68 + lane] * wr2r;
#pragma unroll
      for (int mm = 32; mm; mm >>= 1) v += __shfl_xor(v, mm);
      if (lane == 0 && grow < TOTROWS) out[grow] = sigf(v + br2[0]);
    }
  }
}

// ---------------- batched edge heads
__global__ __launch_bounds__(256) void edge_combine_all(
    const ushort_t* __restrict__ Pcat, const int* __restrict__ ei,
    const float* __restrict__ be1, const float* __restrict__ We2,
    const float* __restrict__ be2, float* __restrict__ out) {
  const int RSI_[7] = {0, 1, 0, 0, 2, 4, 0};
  const int RDI_[7] = {1, 1, 2, 3, 2, 3, 0};
  const int ROFF_[5] = {0, 60000, 80000, 120000, 160000};
  int bb = blockIdx.x;
  int r = bb / 10000;
  int lane = threadIdx.x & 63;
  int e = (bb % 10000) * 4 + (threadIdx.x >> 6);
  const int* src = ei + (size_t)r * 2 * EE;
  const int* dst = src + EE;
  int s = src[e], d = dst[e];
  const ushort_t* p1 = Pcat + ((size_t)(ROFF_[RSI_[r]] + s)) * 256;
  const ushort_t* p2 = Pcat + ((size_t)(ROFF_[RDI_[r]] + d)) * 256 + 128;
  float h0 = eluf(b2f(p1[lane])      + b2f(p2[lane])      + be1[lane]);
  float h1 = eluf(b2f(p1[64 + lane]) + b2f(p2[64 + lane]) + be1[64 + lane]);
  float v = h0 * We2[lane] + h1 * We2[64 + lane];
#pragma unroll
  for (int mm = 32; mm; mm >>= 1) v += __shfl_xor(v, mm);
  if (lane == 0) out[TOTROWS + (size_t)r * EE + e] = sigf(v + be2[0]);
}

extern "C" void kernel_launch(void* const* d_in, const int* in_sizes, int n_in,
                              void* d_out, int out_size, void* d_ws, size_t ws_size,
                              hipStream_t stream) {
  (void)in_sizes; (void)n_in; (void)out_size;
  static const int NCNT_[5] = {60000, 20000, 40000, 40000, 10000};
  static const int RSI[7] = {0, 1, 0, 0, 2, 4, 0};
  static const int RDI[7] = {1, 1, 2, 3, 2, 3, 0};
  static const int RFIRST[7] = {1, 0, 1, 1, 0, 0, 1};
  static const int ROFF[5] = {0, 60000, 80000, 120000, 160000};

  const float* x[5];    for (int i = 0; i < 5; i++) x[i] = (const float*)d_in[i];
  const int*   ei     = (const int*)d_in[5];
  const float* ew     = (const float*)d_in[6];
  const float* theta  = (const float*)d_in[7];
  const float* Win[5]; for (int i = 0; i < 5; i++) Win[i] = (const float*)d_in[8 + i];
  const float* b_in   = (const float*)d_in[13];
  const float* Wq     = (const float*)d_in[14];
  const float* Wk     = (const float*)d_in[15];
  const float* Wv     = (const float*)d_in[16];
  const float* Wmsg   = (const float*)d_in[17];
  const float* bmsg   = (const float*)d_in[18];
  const float* relimp = (const float*)d_in[19];
  const float* Wo     = (const float*)d_in[20];
  const float* bo     = (const float*)d_in[21];
  const float* lng    = (const float*)d_in[22];
  const float* lnb    = (const float*)d_in[23];
  const float* Wr1    = (const float*)d_in[24];
  const float* br1    = (const float*)d_in[25];
  const float* Wr2    = (const float*)d_in[26];
  const float* br2    = (const float*)d_in[27];
  const float* We1    = (const float*)d_in[28];
  const float* be1    = (const float*)d_in[29];
  const float* We2    = (const float*)d_in[30];
  const float* be2    = (const float*)d_in[31];
  float* out = (float*)d_out;

  // ---- workspace ----
  char* ws = (char*)d_ws;
  size_t off = 0;
  auto alloc = [&](size_t bytes) -> void* {
    void* p = (void*)(ws + off);
    off = (off + bytes + 255) & ~(size_t)255;
    return p;
  };
  ushort_t* h    = (ushort_t*)alloc((size_t)TOTROWS * 128 * 2);
  ushort_t* comb = (ushort_t*)alloc((size_t)TOTROWS * 128 * 2);
  ushort_t* Qb   = (ushort_t*)alloc((size_t)60000 * 128 * 2);
  ushort_t* Kb   = (ushort_t*)alloc((size_t)60000 * 128 * 2);
  ushort_t* Vb   = (ushort_t*)alloc((size_t)60000 * 128 * 2);
  ushort_t* Sb   = (ushort_t*)alloc((size_t)60000 * 128 * 2);
  float* degb = (float*)alloc((size_t)60000 * 4);
  ushort_t* Wt = (ushort_t*)alloc((size_t)102 * 16384 * 2);
  int* counts  = (int*)alloc((size_t)7 * NDOFF * 4);
  int* cursor  = (int*)alloc((size_t)7 * NDOFF * 4);
  int* offsb   = (int*)alloc((size_t)7 * NDOFF * 4);
  int* src_csr = (int*)alloc((size_t)7 * EE * 4);
  float* ew_csr = (float*)alloc((size_t)7 * EE * 4);
  int* chunkS  = (int*)alloc((size_t)7 * NCHK * 4);
  int* chunkO  = (int*)alloc((size_t)7 * NCHK * 4);
  float* scal = (float*)alloc(256);
  if (off > ws_size) return;
  ushort_t* Pcat = comb;       // reuse after layers

  prep_scalars<<<1, 64, 0, stream>>>(theta, relimp, scal);
  transpose_weights<<<101, 256, 0, stream>>>(Wq, Wk, Wv, Wmsg, Wo, We1, Wt);
  transpose_wr1<<<32, 256, 0, stream>>>(Wr1, Wt + (size_t)101 * 16384);

  in_proj_all<<<2658, 256, 0, stream>>>(
      x[0], x[1], x[2], x[3], x[4], Win[0], Win[1], Win[2], Win[3], Win[4], b_in, h);

  csr_clear<<<CDIV(7 * NDOFF, 256), 256, 0, stream>>>(counts);
  csr_hist<<<CDIV(7 * EE, 256), 256, 0, stream>>>(ei, counts);
  csr_chunk<<<7 * NCHK, 256, 0, stream>>>(counts, chunkS);
  csr_chunkscan<<<1, 64, 0, stream>>>(chunkS, chunkO);
  csr_scan_final<<<7 * NCHK, 1024, 0, stream>>>(counts, chunkO, offsb, cursor);
  csr_scatter<<<CDIV(7 * EE, 256), 256, 0, stream>>>(ei, ew, cursor, src_csr, ew_csr);

  for (int l = 0; l < 3; l++) {
    for (int r = 0; r < 7; r++) {
      int si = RSI[r], di = RDI[r];
      int nds = NCNT_[si], ndd = NCNT_[di];
      ushort_t* hs = h + (size_t)ROFF[si] * 128;
      ushort_t* hd = h + (size_t)ROFF[di] * 128;
      int lr = l * 7 + r;
      const ushort_t* WtQ = Wt + (size_t)lr * 16384;
      const ushort_t* WtK = Wt + (size_t)(21 + lr) * 16384;
      const ushort_t* WtV = Wt + (size_t)(42 + lr) * 16384;
      int gq = CDIV(ndd, 64), gkv = CDIV(nds, 64);

      if (r == 0) {
        msg_qkv<4><<<gq + gkv, 256, 0, stream>>>(
            nullptr, nullptr, nullptr, 0, scal, scal, scal, 0,
            hd, hs, WtQ, WtK, WtV, Qb, Kb, Vb, ndd, nds);
      } else {
        int pr = r - 1, plr = l * 7 + pr;
        int nmsg = NCNT_[RDI[pr]];
        int gm = CDIV(nmsg, 64);
        ushort_t* pdst = comb + (size_t)ROFF[RDI[pr]] * 128;
        const ushort_t* WtMp = Wt + (size_t)(63 + plr) * 16384;
        if (RFIRST[pr])
          msg_qkv<4><<<gm + gq + gkv, 256, 0, stream>>>(
              Sb, WtMp, pdst, nmsg, scal + 8 + plr, degb, bmsg + (size_t)plr * 128, gm,
              hd, hs, WtQ, WtK, WtV, Qb, Kb, Vb, ndd, nds);
        else
          msg_qkv<1><<<gm + gq + gkv, 256, 0, stream>>>(
              Sb, WtMp, pdst, nmsg, scal + 8 + plr, degb, bmsg + (size_t)plr * 128, gm,
              hd, hs, WtQ, WtK, WtV, Qb, Kb, Vb, ndd, nds);
      }
      attn_agg<<<CDIV(ndd, 8), 512, 0, stream>>>(
          Qb, Kb, Vb, offsb + (size_t)r * NDOFF, src_csr + (size_t)r * EE,
          ew_csr + (size_t)r * EE, scal + r, Sb, degb, ndd);
    }
    // trailing msg for r=6 (RFIRST[6]=1 -> MODE 4)
    {
      int plr = l * 7 + 6;
      int nmsg = NCNT_[RDI[6]];
      int gm = CDIV(nmsg, 64);
      msg_qkv<4><<<gm, 256, 0, stream>>>(
          Sb, Wt + (size_t)(63 + plr) * 16384, comb + (size_t)ROFF[RDI[6]] * 128, nmsg,
          scal + 8 + plr, degb, bmsg + (size_t)plr * 128, gm,
          nullptr, nullptr, nullptr, nullptr, nullptr, nullptr, nullptr, nullptr, 0, 0);
    }
    wo_ln_all<<<WO_TOTAL, 256, 0, stream>>>(h, comb, Wt, bo, lng, lnb, l);
  }

  // ---- heads ----
  pcat_risk<<<2 * G_PCAT, 256, 0, stream>>>(
      h, Wt + (size_t)99 * 16384, Wt + (size_t)100 * 16384, Pcat,
      Wt + (size_t)101 * 16384, br1, Wr2, br2, out);

  edge_combine_all<<<7 * CDIV(EE, 4), 256, 0, stream>>>(Pcat, ei, be1, We2, be2, out);
}